// Round 3
// baseline (418.274 us; speedup 1.0000x reference)
//
#include <hip/hip_runtime.h>

#define B_ 64
#define LC 2048
#define LQ 256
#define DD 128

typedef __bf16 bf16;
typedef __bf16 bf16x8 __attribute__((ext_vector_type(8)));
typedef __bf16 bf16x4 __attribute__((ext_vector_type(4)));
typedef float f32x4 __attribute__((ext_vector_type(4)));

#define MFMA16(a, b, c) __builtin_amdgcn_mfma_f32_16x16x32_bf16((a), (b), (c), 0, 0, 0)

// ---------------------------------------------------------------------------
// K1: prep C: Cw = bf16(C * w4mlu), CbT = bf16(C)^T, CbTm = CbT * Cmask,
//     sub0 = C @ w4C, out block 0 = C^T (fp32 from bf16 data).
// grid: (B*32), 256 threads; tile = 64 c x 128 d
// ---------------------------------------------------------------------------
__global__ __launch_bounds__(256) void k_prep_c(const float* __restrict__ C,
    const float* __restrict__ Cmask, const float* __restrict__ w4C,
    const float* __restrict__ w4mlu, bf16* __restrict__ Cw,
    bf16* __restrict__ CbT, bf16* __restrict__ CbTm,
    float* __restrict__ sub0, float* __restrict__ out)
{
    __shared__ bf16 lds[64][DD + 2];
    __shared__ float ldsM[64];
    int b = blockIdx.x >> 5, ct = blockIdx.x & 31;
    int c0 = ct * 64;
    int t = threadIdx.x;
    int r = t >> 2, cb = (t & 3) * 32;
    size_t rowoff = ((size_t)(b * LC + c0 + r)) * DD + cb;
    const float4* src = (const float4*)(C + rowoff);
    if ((t & 3) == 0) ldsM[r] = Cmask[b * LC + c0 + r];
    float s0 = 0.f;
#pragma unroll
    for (int i = 0; i < 8; ++i) {
        float4 v = src[i];
        int d = cb + i * 4;
        bf16x4 cw = { (bf16)(v.x * w4mlu[d]), (bf16)(v.y * w4mlu[d + 1]),
                      (bf16)(v.z * w4mlu[d + 2]), (bf16)(v.w * w4mlu[d + 3]) };
        *(bf16x4*)(Cw + rowoff + i * 4) = cw;
        lds[r][d]     = (bf16)v.x;
        lds[r][d + 1] = (bf16)v.y;
        lds[r][d + 2] = (bf16)v.z;
        lds[r][d + 3] = (bf16)v.w;
        s0 += v.x * w4C[d] + v.y * w4C[d + 1] + v.z * w4C[d + 2] + v.w * w4C[d + 3];
    }
    s0 += __shfl_xor(s0, 1);
    s0 += __shfl_xor(s0, 2);
    if ((t & 3) == 0) sub0[b * LC + c0 + r] = s0;
    __syncthreads();
    int d = t >> 1, cb2 = (t & 1) * 32;
    bf16* dstT  = CbT  + ((size_t)(b * DD + d)) * LC + c0 + cb2;
    bf16* dstTm = CbTm + ((size_t)(b * DD + d)) * LC + c0 + cb2;
    float* dstO = out + ((size_t)(b * 512 + d)) * LC + c0 + cb2;
#pragma unroll
    for (int m = 0; m < 4; ++m) {
        bf16x8 pk, pm;
        float f[8];
#pragma unroll
        for (int j = 0; j < 8; ++j) {
            bf16 x = lds[cb2 + m * 8 + j][d];
            pk[j] = x;
            f[j] = (float)x;
            pm[j] = (bf16)(f[j] * ldsM[cb2 + m * 8 + j]);
        }
        *(bf16x8*)(dstT + m * 8) = pk;
        *(bf16x8*)(dstTm + m * 8) = pm;
        *(float4*)(dstO + m * 8)     = (float4){f[0], f[1], f[2], f[3]};
        *(float4*)(dstO + m * 8 + 4) = (float4){f[4], f[5], f[6], f[7]};
    }
}

// ---------------------------------------------------------------------------
// K2: prep Q: Qb = bf16(Q), QbT = bf16(Q)^T, sub1 = Q @ w4Q
// ---------------------------------------------------------------------------
__global__ __launch_bounds__(256) void k_prep_q(const float* __restrict__ Q,
    const float* __restrict__ w4Q, bf16* __restrict__ Qb, bf16* __restrict__ QbT,
    float* __restrict__ sub1)
{
    __shared__ bf16 lds[64][DD + 2];
    int b = blockIdx.x >> 2, qt = blockIdx.x & 3;
    int q0 = qt * 64;
    int t = threadIdx.x;
    int r = t >> 2, cb = (t & 3) * 32;
    size_t rowoff = ((size_t)(b * LQ + q0 + r)) * DD + cb;
    const float4* src = (const float4*)(Q + rowoff);
    float s1 = 0.f;
#pragma unroll
    for (int i = 0; i < 8; ++i) {
        float4 v = src[i];
        int d = cb + i * 4;
        bf16x4 qv = { (bf16)v.x, (bf16)v.y, (bf16)v.z, (bf16)v.w };
        *(bf16x4*)(Qb + rowoff + i * 4) = qv;
        lds[r][d]     = qv[0];
        lds[r][d + 1] = qv[1];
        lds[r][d + 2] = qv[2];
        lds[r][d + 3] = qv[3];
        s1 += v.x * w4Q[d] + v.y * w4Q[d + 1] + v.z * w4Q[d + 2] + v.w * w4Q[d + 3];
    }
    s1 += __shfl_xor(s1, 1);
    s1 += __shfl_xor(s1, 2);
    if ((t & 3) == 0) sub1[b * LQ + q0 + r] = s1;
    __syncthreads();
    int d = t >> 1, cb2 = (t & 1) * 32;
    bf16* dst = QbT + ((size_t)(b * DD + d)) * LQ + q0 + cb2;
#pragma unroll
    for (int m = 0; m < 4; ++m) {
        bf16x8 pk;
#pragma unroll
        for (int j = 0; j < 8; ++j) pk[j] = lds[cb2 + m * 8 + j][d];
        *(bf16x8*)(dst + m * 8) = pk;
    }
}

// ---------------------------------------------------------------------------
// K3: S = Cw @ Qb^T + sub0 + sub1 + bias; P = Qmask * exp(S-8) (bf16);
//     Rpart[b][qt][c] = partial rowsum over this block's 64 q;
//     Lpart[b][slice][q] = Cmask-weighted colsum over wave's 32 c.
// grid: (16 ct, 4 qt, B), 256 threads (4 waves); no LDS, no barrier.
// ---------------------------------------------------------------------------
__global__ __launch_bounds__(256) void k_s(const bf16* __restrict__ Cw,
    const bf16* __restrict__ Qb, const float* __restrict__ sub0,
    const float* __restrict__ sub1, const float* __restrict__ Qmask,
    const float* __restrict__ Cmask, const float* __restrict__ bias,
    bf16* __restrict__ P, float* __restrict__ Rpart, float* __restrict__ Lpart)
{
    int b = blockIdx.z, qt = blockIdx.y, ctile = blockIdx.x;
    int q0 = qt * 64;
    int t = threadIdx.x, wid = t >> 6, lane = t & 63;
    int lr = lane & 15, lg = lane >> 4;
    int rowbase = ctile * 128 + wid * 32;

    f32x4 acc[2][4];
#pragma unroll
    for (int rt = 0; rt < 2; ++rt)
#pragma unroll
        for (int ct = 0; ct < 4; ++ct) acc[rt][ct] = (f32x4){0.f, 0.f, 0.f, 0.f};

    const bf16* Abase = Cw + ((size_t)(b * LC + rowbase + lr)) * DD + lg * 8;
    const bf16* Bbase = Qb + ((size_t)(b * LQ + q0 + lr)) * DD + lg * 8;
#pragma unroll
    for (int ks = 0; ks < 4; ++ks) {
        bf16x8 a0 = *(const bf16x8*)(Abase + ks * 32);
        bf16x8 a1 = *(const bf16x8*)(Abase + 16 * DD + ks * 32);
#pragma unroll
        for (int ct = 0; ct < 4; ++ct) {
            bf16x8 bb = *(const bf16x8*)(Bbase + (size_t)ct * 16 * DD + ks * 32);
            acc[0][ct] = MFMA16(a0, bb, acc[0][ct]);
            acc[1][ct] = MFMA16(a1, bb, acc[1][ct]);
        }
    }

    float biasv = bias[0];
    float sub0v[2][4], cmv[2][4];
#pragma unroll
    for (int rt = 0; rt < 2; ++rt)
#pragma unroll
        for (int j = 0; j < 4; ++j) {
            int idx = b * LC + rowbase + rt * 16 + lg * 4 + j;
            sub0v[rt][j] = sub0[idx];
            cmv[rt][j] = Cmask[idx];
        }

    float rsum[2][4] = {};
#pragma unroll
    for (int ct = 0; ct < 4; ++ct) {
        int q = q0 + ct * 16 + lr;
        float s1v = sub1[b * LQ + q] + biasv;
        float qm = Qmask[b * LQ + q];
        float colsum = 0.f;
#pragma unroll
        for (int rt = 0; rt < 2; ++rt)
#pragma unroll
            for (int j = 0; j < 4; ++j) {
                float S = acc[rt][ct][j] + sub0v[rt][j] + s1v;
                float Pv = __expf(S - 8.0f) * qm;
                rsum[rt][j] += Pv;
                colsum += Pv * cmv[rt][j];
                P[((size_t)(b * LC + rowbase + rt * 16 + lg * 4 + j)) * LQ + q] = (bf16)Pv;
            }
        colsum += __shfl_xor(colsum, 16);
        colsum += __shfl_xor(colsum, 32);
        if (lg == 0)
            Lpart[((size_t)(b * 64 + ctile * 4 + wid)) * LQ + q] = colsum;
    }
#pragma unroll
    for (int rt = 0; rt < 2; ++rt)
#pragma unroll
        for (int j = 0; j < 4; ++j) {
            float s = rsum[rt][j];
            s += __shfl_xor(s, 1);
            s += __shfl_xor(s, 2);
            s += __shfl_xor(s, 4);
            s += __shfl_xor(s, 8);
            if (lr == 0)
                Rpart[((size_t)(b * 4 + qt)) * LC + rowbase + rt * 16 + lg * 4 + j] = s;
        }
}

// ---------------------------------------------------------------------------
// K4: K-split partial: MTp[ksl][b][d][q] = sum over 256 c of CbTm[d][c]*P[c][q]
// grid: (4 qt, 8 ksl, B), 256 threads (4 waves); wave = 32d x 64q; no LDS/barrier.
// B-fragments gathered as 8 scalar bf16 loads (stride LQ) from P.
// ---------------------------------------------------------------------------
__global__ __launch_bounds__(256) void k_m(const bf16* __restrict__ CbTm,
    const bf16* __restrict__ P, bf16* __restrict__ MTp)
{
    int b = blockIdx.z, ksl = blockIdx.y, qt = blockIdx.x;
    int q0 = qt * 64, c0 = ksl * 256;
    int t = threadIdx.x, wid = t >> 6, lane = t & 63;
    int lr = lane & 15, lg = lane >> 4;
    int dbase = wid * 32;

    f32x4 acc[2][4];
#pragma unroll
    for (int rt = 0; rt < 2; ++rt)
#pragma unroll
        for (int ct = 0; ct < 4; ++ct) acc[rt][ct] = (f32x4){0.f, 0.f, 0.f, 0.f};

    const bf16* Abase = CbTm + ((size_t)(b * DD + dbase + lr)) * LC + c0 + lg * 8;
#pragma unroll 2
    for (int ks = 0; ks < 8; ++ks) {
        bf16x8 a0 = *(const bf16x8*)(Abase + ks * 32);
        bf16x8 a1 = *(const bf16x8*)(Abase + (size_t)16 * LC + ks * 32);
#pragma unroll
        for (int ct = 0; ct < 4; ++ct) {
            bf16x8 bb;
#pragma unroll
            for (int i = 0; i < 8; ++i)
                bb[i] = P[((size_t)(b * LC + c0 + ks * 32 + lg * 8 + i)) * LQ + q0 + ct * 16 + lr];
            acc[0][ct] = MFMA16(a0, bb, acc[0][ct]);
            acc[1][ct] = MFMA16(a1, bb, acc[1][ct]);
        }
    }
#pragma unroll
    for (int ct = 0; ct < 4; ++ct)
#pragma unroll
        for (int rt = 0; rt < 2; ++rt)
#pragma unroll
            for (int j = 0; j < 4; ++j)
                MTp[(((size_t)ksl * B_ + b) * DD + dbase + rt * 16 + lg * 4 + j) * LQ
                    + q0 + ct * 16 + lr] = (bf16)acc[rt][ct][j];
}

// ---------------------------------------------------------------------------
// K5: reduce 8 partials + fold Linv (from 64 Lpart slices): MT[b][d][q] bf16
// grid: (8 dch, B), 256 threads; thread = one q column, 16 d rows.
// ---------------------------------------------------------------------------
__global__ __launch_bounds__(256) void k_m2(const bf16* __restrict__ MTp,
    const float* __restrict__ Lpart, bf16* __restrict__ MT)
{
    int b = blockIdx.y, dch = blockIdx.x;
    int q = threadIdx.x;
    float ls = 0.f;
#pragma unroll
    for (int s = 0; s < 64; ++s) ls += Lpart[((size_t)(b * 64 + s)) * LQ + q];
    float linv = 1.0f / fmaxf(ls, 1e-30f);
#pragma unroll
    for (int i = 0; i < 16; ++i) {
        int d = dch * 16 + i;
        float a = 0.f;
#pragma unroll
        for (int s = 0; s < 8; ++s)
            a += (float)MTp[(((size_t)s * B_ + b) * DD + d) * LQ + q];
        MT[((size_t)(b * DD + d)) * LQ + q] = (bf16)(a * linv);
    }
}

// ---------------------------------------------------------------------------
// K6: AT-direct output: A^T = Qb^T @ P^T via MFMA(A=P rows c, B=QbT rows d)
//     -> lane owns 4 consecutive c at one d => float4 stores in out layout.
//     Writes blocks 1 (A), 2 (C*A), 3 (C*Bt). No LDS, no barriers.
// grid: (32 ctile, B), 256 threads (4 waves); wave = 16 c x 128 d.
// ---------------------------------------------------------------------------
__global__ __launch_bounds__(256) void k_out(const bf16* __restrict__ P,
    const bf16* __restrict__ QbT, const bf16* __restrict__ MT,
    const bf16* __restrict__ CbT, const float* __restrict__ Rpart,
    float* __restrict__ out)
{
    int b = blockIdx.y, ctile = blockIdx.x;
    int t = threadIdx.x, wid = t >> 6, lane = t & 63;
    int lr = lane & 15, lg = lane >> 4;
    int c0 = ctile * 64 + wid * 16;

    f32x4 accA[8], accB[8];
#pragma unroll
    for (int dt = 0; dt < 8; ++dt) {
        accA[dt] = (f32x4){0.f, 0.f, 0.f, 0.f};
        accB[dt] = (f32x4){0.f, 0.f, 0.f, 0.f};
    }
    const bf16* Abase = P + ((size_t)(b * LC + c0 + lr)) * LQ + lg * 8;
    const bf16* Qbase = QbT + ((size_t)(b * DD + lr)) * LQ + lg * 8;
    const bf16* Mbase = MT + ((size_t)(b * DD + lr)) * LQ + lg * 8;
#pragma unroll
    for (int ks = 0; ks < 8; ++ks) {
        bf16x8 a = *(const bf16x8*)(Abase + ks * 32);
#pragma unroll
        for (int dt = 0; dt < 8; ++dt) {
            bf16x8 bq = *(const bf16x8*)(Qbase + (size_t)dt * 16 * LQ + ks * 32);
            bf16x8 bm = *(const bf16x8*)(Mbase + (size_t)dt * 16 * LQ + ks * 32);
            accA[dt] = MFMA16(a, bq, accA[dt]);
            accB[dt] = MFMA16(a, bm, accB[dt]);
        }
    }
    f32x4 rs = (f32x4){0.f, 0.f, 0.f, 0.f};
#pragma unroll
    for (int s = 0; s < 4; ++s)
        rs += *(const f32x4*)(Rpart + ((size_t)(b * 4 + s)) * LC + c0 + lg * 4);
    f32x4 rv;
#pragma unroll
    for (int j = 0; j < 4; ++j) rv[j] = 1.0f / fmaxf(rs[j], 1e-30f);

    float* obase = out + ((size_t)b * 512) * LC;
#pragma unroll
    for (int dt = 0; dt < 8; ++dt) {
        int d = dt * 16 + lr;
        bf16x4 cb4 = *(const bf16x4*)(CbT + ((size_t)(b * DD + d)) * LC + c0 + lg * 4);
        f32x4 c4 = {(float)cb4[0], (float)cb4[1], (float)cb4[2], (float)cb4[3]};
        f32x4 a4 = accA[dt] * rv;
        f32x4 b4 = accB[dt] * rv;
        *(f32x4*)(obase + (size_t)(128 + d) * LC + c0 + lg * 4) = a4;
        *(f32x4*)(obase + (size_t)(256 + d) * LC + c0 + lg * 4) = c4 * a4;
        *(f32x4*)(obase + (size_t)(384 + d) * LC + c0 + lg * 4) = c4 * b4;
    }
}

// ---------------------------------------------------------------------------
extern "C" void kernel_launch(void* const* d_in, const int* in_sizes, int n_in,
                              void* d_out, int out_size, void* d_ws, size_t ws_size,
                              hipStream_t stream)
{
    const float* C     = (const float*)d_in[0];
    const float* Q     = (const float*)d_in[1];
    const float* Cmask = (const float*)d_in[2];
    const float* Qmask = (const float*)d_in[3];
    const float* w4C   = (const float*)d_in[4];
    const float* w4Q   = (const float*)d_in[5];
    const float* w4mlu = (const float*)d_in[6];
    const float* bias  = (const float*)d_in[7];
    float* out = (float*)d_out;

    char* ws = (char*)d_ws;
    size_t off = 0;
    auto alloc = [&](size_t bytes) -> char* {
        char* p = ws + off;
        off += (bytes + 255) & ~(size_t)255;
        return p;
    };
    bf16* Cw    = (bf16*)alloc((size_t)B_ * LC * DD * 2);
    bf16* CbT   = (bf16*)alloc((size_t)B_ * LC * DD * 2);
    bf16* CbTm  = (bf16*)alloc((size_t)B_ * LC * DD * 2);
    bf16* Qb    = (bf16*)alloc((size_t)B_ * LQ * DD * 2);
    bf16* QbT   = (bf16*)alloc((size_t)B_ * LQ * DD * 2);
    bf16* Pbuf  = (bf16*)alloc((size_t)B_ * LC * LQ * 2);
    bf16* MTp   = (bf16*)alloc((size_t)8 * B_ * DD * LQ * 2);
    bf16* MT    = (bf16*)alloc((size_t)B_ * DD * LQ * 2);
    float* sub0 = (float*)alloc((size_t)B_ * LC * 4);
    float* sub1 = (float*)alloc((size_t)B_ * LQ * 4);
    float* Rpart = (float*)alloc((size_t)B_ * 4 * LC * 4);
    float* Lpart = (float*)alloc((size_t)B_ * 64 * LQ * 4);
    (void)ws_size; (void)in_sizes; (void)n_in; (void)out_size;

    hipLaunchKernelGGL(k_prep_c, dim3(B_ * 32), dim3(256), 0, stream,
                       C, Cmask, w4C, w4mlu, Cw, CbT, CbTm, sub0, out);
    hipLaunchKernelGGL(k_prep_q, dim3(B_ * 4), dim3(256), 0, stream,
                       Q, w4Q, Qb, QbT, sub1);
    hipLaunchKernelGGL(k_s, dim3(16, 4, B_), dim3(256), 0, stream,
                       Cw, Qb, sub0, sub1, Qmask, Cmask, bias, Pbuf, Rpart, Lpart);
    hipLaunchKernelGGL(k_m, dim3(4, 8, B_), dim3(256), 0, stream, CbTm, Pbuf, MTp);
    hipLaunchKernelGGL(k_m2, dim3(8, B_), dim3(256), 0, stream, MTp, Lpart, MT);
    hipLaunchKernelGGL(k_out, dim3(32, B_), dim3(256), 0, stream,
                       Pbuf, QbT, MT, CbT, Rpart, out);
}

// Round 4
// 394.127 us; speedup vs baseline: 1.0613x; 1.0613x over previous
//
#include <hip/hip_runtime.h>

#define B_ 64
#define LC 2048
#define LQ 256
#define DD 128

typedef __bf16 bf16;
typedef __bf16 bf16x8 __attribute__((ext_vector_type(8)));
typedef __bf16 bf16x4 __attribute__((ext_vector_type(4)));
typedef float f32x4 __attribute__((ext_vector_type(4)));

#define MFMA16(a, b, c) __builtin_amdgcn_mfma_f32_16x16x32_bf16((a), (b), (c), 0, 0, 0)

// ---------------------------------------------------------------------------
// K1: prep C: Cw = bf16(C * w4mlu), CbT = bf16(C)^T, sub0 = C @ w4C,
//     out block 0 = C^T (fp32 from bf16 data).
// grid: (B*32), 256 threads; tile = 64 c x 128 d
// ---------------------------------------------------------------------------
__global__ __launch_bounds__(256) void k_prep_c(const float* __restrict__ C,
    const float* __restrict__ w4C, const float* __restrict__ w4mlu,
    bf16* __restrict__ Cw, bf16* __restrict__ CbT,
    float* __restrict__ sub0, float* __restrict__ out)
{
    __shared__ bf16 lds[64][DD + 2];
    int b = blockIdx.x >> 5, ct = blockIdx.x & 31;
    int c0 = ct * 64;
    int t = threadIdx.x;
    int r = t >> 2, cb = (t & 3) * 32;
    size_t rowoff = ((size_t)(b * LC + c0 + r)) * DD + cb;
    const float4* src = (const float4*)(C + rowoff);
    float s0 = 0.f;
#pragma unroll
    for (int i = 0; i < 8; ++i) {
        float4 v = src[i];
        int d = cb + i * 4;
        bf16x4 cw = { (bf16)(v.x * w4mlu[d]), (bf16)(v.y * w4mlu[d + 1]),
                      (bf16)(v.z * w4mlu[d + 2]), (bf16)(v.w * w4mlu[d + 3]) };
        *(bf16x4*)(Cw + rowoff + i * 4) = cw;
        lds[r][d]     = (bf16)v.x;
        lds[r][d + 1] = (bf16)v.y;
        lds[r][d + 2] = (bf16)v.z;
        lds[r][d + 3] = (bf16)v.w;
        s0 += v.x * w4C[d] + v.y * w4C[d + 1] + v.z * w4C[d + 2] + v.w * w4C[d + 3];
    }
    s0 += __shfl_xor(s0, 1);
    s0 += __shfl_xor(s0, 2);
    if ((t & 3) == 0) sub0[b * LC + c0 + r] = s0;
    __syncthreads();
    int d = t >> 1, cb2 = (t & 1) * 32;
    bf16* dstT  = CbT + ((size_t)(b * DD + d)) * LC + c0 + cb2;
    float* dstO = out + ((size_t)(b * 512 + d)) * LC + c0 + cb2;
#pragma unroll
    for (int m = 0; m < 4; ++m) {
        bf16x8 pk;
        float f[8];
#pragma unroll
        for (int j = 0; j < 8; ++j) {
            bf16 x = lds[cb2 + m * 8 + j][d];
            pk[j] = x;
            f[j] = (float)x;
        }
        *(bf16x8*)(dstT + m * 8) = pk;
        *(float4*)(dstO + m * 8)     = (float4){f[0], f[1], f[2], f[3]};
        *(float4*)(dstO + m * 8 + 4) = (float4){f[4], f[5], f[6], f[7]};
    }
}

// ---------------------------------------------------------------------------
// K2: prep Q: Qb = bf16(Q), QbT = bf16(Q)^T, sub1 = Q @ w4Q
// ---------------------------------------------------------------------------
__global__ __launch_bounds__(256) void k_prep_q(const float* __restrict__ Q,
    const float* __restrict__ w4Q, bf16* __restrict__ Qb, bf16* __restrict__ QbT,
    float* __restrict__ sub1)
{
    __shared__ bf16 lds[64][DD + 2];
    int b = blockIdx.x >> 2, qt = blockIdx.x & 3;
    int q0 = qt * 64;
    int t = threadIdx.x;
    int r = t >> 2, cb = (t & 3) * 32;
    size_t rowoff = ((size_t)(b * LQ + q0 + r)) * DD + cb;
    const float4* src = (const float4*)(Q + rowoff);
    float s1 = 0.f;
#pragma unroll
    for (int i = 0; i < 8; ++i) {
        float4 v = src[i];
        int d = cb + i * 4;
        bf16x4 qv = { (bf16)v.x, (bf16)v.y, (bf16)v.z, (bf16)v.w };
        *(bf16x4*)(Qb + rowoff + i * 4) = qv;
        lds[r][d]     = qv[0];
        lds[r][d + 1] = qv[1];
        lds[r][d + 2] = qv[2];
        lds[r][d + 3] = qv[3];
        s1 += v.x * w4Q[d] + v.y * w4Q[d + 1] + v.z * w4Q[d + 2] + v.w * w4Q[d + 3];
    }
    s1 += __shfl_xor(s1, 1);
    s1 += __shfl_xor(s1, 2);
    if ((t & 3) == 0) sub1[b * LQ + q0 + r] = s1;
    __syncthreads();
    int d = t >> 1, cb2 = (t & 1) * 32;
    bf16* dst = QbT + ((size_t)(b * DD + d)) * LQ + q0 + cb2;
#pragma unroll
    for (int m = 0; m < 4; ++m) {
        bf16x8 pk;
#pragma unroll
        for (int j = 0; j < 8; ++j) pk[j] = lds[cb2 + m * 8 + j][d];
        *(bf16x8*)(dst + m * 8) = pk;
    }
}

// ---------------------------------------------------------------------------
// K3: S = Cw @ Qb^T + sub0 + sub1 + bias; P = Qmask*exp(S-8);
//     P streamed c-major, PT = Cmask*P streamed q-major (both via LDS, coalesced).
//     Rpart[b][qt][c] partial rowsums; Lpart[b][slice][q] masked colsums.
// grid: (16 ct, 4 qt, B), 256 threads (4 waves); block = 128 c x 64 q.
// ---------------------------------------------------------------------------
__global__ __launch_bounds__(256) void k_s(const bf16* __restrict__ Cw,
    const bf16* __restrict__ Qb, const float* __restrict__ sub0,
    const float* __restrict__ sub1, const float* __restrict__ Qmask,
    const float* __restrict__ Cmask, const float* __restrict__ bias,
    bf16* __restrict__ P, bf16* __restrict__ PT,
    float* __restrict__ Rpart, float* __restrict__ Lpart)
{
    __shared__ bf16 ldsP[128][72];    // [c_local][q_local]
    __shared__ bf16 ldsPT[64][136];   // [q_local][c_local]
    int b = blockIdx.z, qt = blockIdx.y, ctile = blockIdx.x;
    int q0 = qt * 64;
    int t = threadIdx.x, wid = t >> 6, lane = t & 63;
    int lr = lane & 15, lg = lane >> 4;
    int rowbase = ctile * 128 + wid * 32;

    f32x4 acc[2][4];
#pragma unroll
    for (int rt = 0; rt < 2; ++rt)
#pragma unroll
        for (int ct = 0; ct < 4; ++ct) acc[rt][ct] = (f32x4){0.f, 0.f, 0.f, 0.f};

    const bf16* Abase = Cw + ((size_t)(b * LC + rowbase + lr)) * DD + lg * 8;
    const bf16* Bbase = Qb + ((size_t)(b * LQ + q0 + lr)) * DD + lg * 8;
#pragma unroll
    for (int ks = 0; ks < 4; ++ks) {
        bf16x8 a0 = *(const bf16x8*)(Abase + ks * 32);
        bf16x8 a1 = *(const bf16x8*)(Abase + 16 * DD + ks * 32);
#pragma unroll
        for (int ct = 0; ct < 4; ++ct) {
            bf16x8 bb = *(const bf16x8*)(Bbase + (size_t)ct * 16 * DD + ks * 32);
            acc[0][ct] = MFMA16(a0, bb, acc[0][ct]);
            acc[1][ct] = MFMA16(a1, bb, acc[1][ct]);
        }
    }

    float biasv = bias[0];
    float sub0v[2][4], cmv[2][4];
#pragma unroll
    for (int rt = 0; rt < 2; ++rt)
#pragma unroll
        for (int j = 0; j < 4; ++j) {
            int idx = b * LC + rowbase + rt * 16 + lg * 4 + j;
            sub0v[rt][j] = sub0[idx];
            cmv[rt][j] = Cmask[idx];
        }

    float rsum[2][4] = {};
#pragma unroll
    for (int ct = 0; ct < 4; ++ct) {
        int q = q0 + ct * 16 + lr;
        float s1v = sub1[b * LQ + q] + biasv;
        float qm = Qmask[b * LQ + q];
        float colsum = 0.f;
#pragma unroll
        for (int rt = 0; rt < 2; ++rt) {
            bf16x4 ptv;
#pragma unroll
            for (int j = 0; j < 4; ++j) {
                float S = acc[rt][ct][j] + sub0v[rt][j] + s1v;
                float Pv = __expf(S - 8.0f) * qm;
                rsum[rt][j] += Pv;
                float pm = Pv * cmv[rt][j];
                colsum += pm;
                ptv[j] = (bf16)pm;
                ldsP[wid * 32 + rt * 16 + lg * 4 + j][ct * 16 + lr] = (bf16)Pv;
            }
            *(bf16x4*)&ldsPT[ct * 16 + lr][wid * 32 + rt * 16 + lg * 4] = ptv;
        }
        colsum += __shfl_xor(colsum, 16);
        colsum += __shfl_xor(colsum, 32);
        if (lg == 0)
            Lpart[((size_t)(b * 64 + ctile * 4 + wid)) * LQ + q] = colsum;
    }
#pragma unroll
    for (int rt = 0; rt < 2; ++rt)
#pragma unroll
        for (int j = 0; j < 4; ++j) {
            float s = rsum[rt][j];
            s += __shfl_xor(s, 1);
            s += __shfl_xor(s, 2);
            s += __shfl_xor(s, 4);
            s += __shfl_xor(s, 8);
            if (lr == 0)
                Rpart[((size_t)(b * 4 + qt)) * LC + rowbase + rt * 16 + lg * 4 + j] = s;
        }
    __syncthreads();

    // stream P rows (c-major): 8 lanes x 16B = 128-B runs
#pragma unroll
    for (int pass = 0; pass < 4; ++pass) {
        int c = pass * 32 + (t >> 3);
        int qo = (t & 7) * 8;
        bf16x8 v = *(bf16x8*)&ldsP[c][qo];
        *(bf16x8*)(P + ((size_t)(b * LC + ctile * 128 + c)) * LQ + q0 + qo) = v;
    }
    // stream PT rows (q-major): 16 lanes x 16B = 256-B runs
#pragma unroll
    for (int pass = 0; pass < 4; ++pass) {
        int ql = pass * 16 + (t >> 4);
        int co = (t & 15) * 8;
        bf16x8 v = *(bf16x8*)&ldsPT[ql][co];
        *(bf16x8*)(PT + ((size_t)(b * LQ + q0 + ql)) * LC + ctile * 128 + co) = v;
    }
}

// ---------------------------------------------------------------------------
// K4: K-split partial: MTp slice = sum over 256 c of CbT[d][c] * PT[q][c]
//     (Cmask already folded into PT). Output in MFMA-native flat layout ->
//     fully coalesced 128-B stores. grid: (4 qt, 8 ksl, B), 256 threads.
// ---------------------------------------------------------------------------
__global__ __launch_bounds__(256) void k_m(const bf16* __restrict__ CbT,
    const bf16* __restrict__ PT, bf16* __restrict__ MTp)
{
    int b = blockIdx.z, ksl = blockIdx.y, qt = blockIdx.x;
    int q0 = qt * 64, c0 = ksl * 256;
    int t = threadIdx.x, wid = t >> 6, lane = t & 63;
    int lr = lane & 15, lg = lane >> 4;
    int dbase = wid * 32;

    f32x4 acc[2][4];
#pragma unroll
    for (int rt = 0; rt < 2; ++rt)
#pragma unroll
        for (int ct = 0; ct < 4; ++ct) acc[rt][ct] = (f32x4){0.f, 0.f, 0.f, 0.f};

    const bf16* Abase = CbT + ((size_t)(b * DD + dbase + lr)) * LC + c0 + lg * 8;
    const bf16* Bbase = PT + ((size_t)(b * LQ + q0 + lr)) * LC + c0 + lg * 8;
#pragma unroll 2
    for (int ks = 0; ks < 8; ++ks) {
        bf16x8 a0 = *(const bf16x8*)(Abase + ks * 32);
        bf16x8 a1 = *(const bf16x8*)(Abase + (size_t)16 * LC + ks * 32);
#pragma unroll
        for (int ct = 0; ct < 4; ++ct) {
            bf16x8 bb = *(const bf16x8*)(Bbase + (size_t)ct * 16 * LC + ks * 32);
            acc[0][ct] = MFMA16(a0, bb, acc[0][ct]);
            acc[1][ct] = MFMA16(a1, bb, acc[1][ct]);
        }
    }
    size_t base = ((((size_t)ksl * B_ + b) * 4 + qt) * 4 + wid) * 2048;
#pragma unroll
    for (int rt = 0; rt < 2; ++rt)
#pragma unroll
        for (int ct = 0; ct < 4; ++ct)
#pragma unroll
            for (int j = 0; j < 4; ++j)
                MTp[base + (size_t)(rt * 16 + ct * 4 + j) * 64 + lane] = (bf16)acc[rt][ct][j];
}

// ---------------------------------------------------------------------------
// K5: reduce 8 K-slices (native layout, coalesced reads) + fold Linv -> MT[d][q]
// grid: (4 qt, B), 256 threads.
// ---------------------------------------------------------------------------
__global__ __launch_bounds__(256) void k_m2(const bf16* __restrict__ MTp,
    const float* __restrict__ Lpart, bf16* __restrict__ MT)
{
    __shared__ float ldsLinv[64];
    int b = blockIdx.y, qt = blockIdx.x;
    int q0 = qt * 64;
    int t = threadIdx.x, lane = t & 63, widx = t >> 6;
    if (t < 64) {
        float s = 0.f;
#pragma unroll
        for (int sl = 0; sl < 64; ++sl) s += Lpart[((size_t)(b * 64 + sl)) * LQ + q0 + t];
        ldsLinv[t] = 1.0f / fmaxf(s, 1e-30f);
    }
    __syncthreads();
    int lr = lane & 15, lg = lane >> 4;
#pragma unroll
    for (int al = 0; al < 32; ++al) {
        float v = 0.f;
#pragma unroll
        for (int sl = 0; sl < 8; ++sl)
            v += (float)MTp[(((size_t)sl * B_ + b) * 4 + qt) * 8192 + (size_t)widx * 2048
                            + (size_t)al * 64 + lane];
        int rt = al >> 4, ct = (al >> 2) & 3, j = al & 3;
        float li = ldsLinv[ct * 16 + lr];
        int d = widx * 32 + rt * 16 + lg * 4 + j;
        MT[((size_t)(b * DD + d)) * LQ + q0 + ct * 16 + lr] = (bf16)(v * li);
    }
}

// ---------------------------------------------------------------------------
// K6: A = Rinv*(P @ Qb), Bt = Rinv*(P @ M). Pack scaled accs to bf16 LDS
//     (36KB -> 4 blocks/CU), ONE sync, then 256-B-run float4 stores.
//     Writes out blocks 1 (A), 2 (C*A), 3 (C*Bt).
// grid: (32 ctile, B), 256 threads (4 waves).
// ---------------------------------------------------------------------------
__global__ __launch_bounds__(256) void k_out(const bf16* __restrict__ P,
    const bf16* __restrict__ QbT, const bf16* __restrict__ MT,
    const bf16* __restrict__ CbT, const float* __restrict__ Rpart,
    float* __restrict__ out)
{
    __shared__ bf16 ldsA[DD][72];   // [d][c_local]
    __shared__ bf16 ldsB[DD][72];
    int b = blockIdx.y, ctile = blockIdx.x;
    int t = threadIdx.x, wid = t >> 6, lane = t & 63;
    int lr = lane & 15, lg = lane >> 4;
    int c0 = ctile * 64;

    f32x4 accA[8], accB[8];
#pragma unroll
    for (int dt = 0; dt < 8; ++dt) {
        accA[dt] = (f32x4){0.f, 0.f, 0.f, 0.f};
        accB[dt] = (f32x4){0.f, 0.f, 0.f, 0.f};
    }
    const bf16* Abase = P + ((size_t)(b * LC + c0 + wid * 16 + lr)) * LQ + lg * 8;
    const bf16* Qbase = QbT + ((size_t)(b * DD + lr)) * LQ + lg * 8;
    const bf16* Mbase = MT + ((size_t)(b * DD + lr)) * LQ + lg * 8;
#pragma unroll
    for (int ks = 0; ks < 8; ++ks) {
        bf16x8 a = *(const bf16x8*)(Abase + ks * 32);
#pragma unroll
        for (int dt = 0; dt < 8; ++dt) {
            bf16x8 bq = *(const bf16x8*)(Qbase + (size_t)dt * 16 * LQ + ks * 32);
            bf16x8 bm = *(const bf16x8*)(Mbase + (size_t)dt * 16 * LQ + ks * 32);
            accA[dt] = MFMA16(a, bq, accA[dt]);
            accB[dt] = MFMA16(a, bm, accB[dt]);
        }
    }
    f32x4 rs = (f32x4){0.f, 0.f, 0.f, 0.f};
#pragma unroll
    for (int s = 0; s < 4; ++s)
        rs += *(const f32x4*)(Rpart + ((size_t)(b * 4 + s)) * LC + c0 + wid * 16 + lg * 4);
    f32x4 rv;
#pragma unroll
    for (int j = 0; j < 4; ++j) rv[j] = 1.0f / fmaxf(rs[j], 1e-30f);

#pragma unroll
    for (int dt = 0; dt < 8; ++dt) {
        f32x4 a4 = accA[dt] * rv;
        f32x4 b4 = accB[dt] * rv;
        bf16x4 pa = { (bf16)a4[0], (bf16)a4[1], (bf16)a4[2], (bf16)a4[3] };
        bf16x4 pb = { (bf16)b4[0], (bf16)b4[1], (bf16)b4[2], (bf16)b4[3] };
        *(bf16x4*)&ldsA[dt * 16 + lr][wid * 16 + lg * 4] = pa;
        *(bf16x4*)&ldsB[dt * 16 + lr][wid * 16 + lg * 4] = pb;
    }
    __syncthreads();

    float* obase = out + ((size_t)b * 512) * LC;
#pragma unroll
    for (int pass = 0; pass < 8; ++pass) {
        int d = pass * 16 + (t >> 4);
        int cq = (t & 15) * 4;
        bf16x4 av = *(bf16x4*)&ldsA[d][cq];
        bf16x4 bv = *(bf16x4*)&ldsB[d][cq];
        bf16x4 cb4 = *(const bf16x4*)(CbT + ((size_t)(b * DD + d)) * LC + c0 + cq);
        float4 c4 = {(float)cb4[0], (float)cb4[1], (float)cb4[2], (float)cb4[3]};
        float4 a4 = {(float)av[0], (float)av[1], (float)av[2], (float)av[3]};
        float4 b4 = {(float)bv[0], (float)bv[1], (float)bv[2], (float)bv[3]};
        *(float4*)(obase + (size_t)(128 + d) * LC + c0 + cq) = a4;
        *(float4*)(obase + (size_t)(256 + d) * LC + c0 + cq) =
            (float4){c4.x * a4.x, c4.y * a4.y, c4.z * a4.z, c4.w * a4.w};
        *(float4*)(obase + (size_t)(384 + d) * LC + c0 + cq) =
            (float4){c4.x * b4.x, c4.y * b4.y, c4.z * b4.z, c4.w * b4.w};
    }
}

// ---------------------------------------------------------------------------
extern "C" void kernel_launch(void* const* d_in, const int* in_sizes, int n_in,
                              void* d_out, int out_size, void* d_ws, size_t ws_size,
                              hipStream_t stream)
{
    const float* C     = (const float*)d_in[0];
    const float* Q     = (const float*)d_in[1];
    const float* Cmask = (const float*)d_in[2];
    const float* Qmask = (const float*)d_in[3];
    const float* w4C   = (const float*)d_in[4];
    const float* w4Q   = (const float*)d_in[5];
    const float* w4mlu = (const float*)d_in[6];
    const float* bias  = (const float*)d_in[7];
    float* out = (float*)d_out;

    char* ws = (char*)d_ws;
    size_t off = 0;
    auto alloc = [&](size_t bytes) -> char* {
        char* p = ws + off;
        off += (bytes + 255) & ~(size_t)255;
        return p;
    };
    bf16* Cw    = (bf16*)alloc((size_t)B_ * LC * DD * 2);   // dead after k_s; reused as MTp
    bf16* CbT   = (bf16*)alloc((size_t)B_ * LC * DD * 2);
    bf16* Qb    = (bf16*)alloc((size_t)B_ * LQ * DD * 2);
    bf16* QbT   = (bf16*)alloc((size_t)B_ * LQ * DD * 2);
    bf16* Pbuf  = (bf16*)alloc((size_t)B_ * LC * LQ * 2);
    bf16* PT    = (bf16*)alloc((size_t)B_ * LC * LQ * 2);
    bf16* MT    = (bf16*)alloc((size_t)B_ * DD * LQ * 2);
    float* sub0 = (float*)alloc((size_t)B_ * LC * 4);
    float* sub1 = (float*)alloc((size_t)B_ * LQ * 4);
    float* Rpart = (float*)alloc((size_t)B_ * 4 * LC * 4);
    float* Lpart = (float*)alloc((size_t)B_ * 64 * LQ * 4);
    bf16* MTp = Cw;  // alias: Cw (33.5MB) is dead once k_s completes; MTp same size
    (void)ws_size; (void)in_sizes; (void)n_in; (void)out_size;

    hipLaunchKernelGGL(k_prep_c, dim3(B_ * 32), dim3(256), 0, stream,
                       C, w4C, w4mlu, Cw, CbT, sub0, out);
    hipLaunchKernelGGL(k_prep_q, dim3(B_ * 4), dim3(256), 0, stream,
                       Q, w4Q, Qb, QbT, sub1);
    hipLaunchKernelGGL(k_s, dim3(16, 4, B_), dim3(256), 0, stream,
                       Cw, Qb, sub0, sub1, Qmask, Cmask, bias, Pbuf, PT, Rpart, Lpart);
    hipLaunchKernelGGL(k_m, dim3(4, 8, B_), dim3(256), 0, stream, CbT, PT, MTp);
    hipLaunchKernelGGL(k_m2, dim3(4, B_), dim3(256), 0, stream, MTp, Lpart, MT);
    hipLaunchKernelGGL(k_out, dim3(32, B_), dim3(256), 0, stream,
                       Pbuf, QbT, MT, CbT, Rpart, out);
}

// Round 5
// 307.436 us; speedup vs baseline: 1.3605x; 1.2820x over previous
//
#include <hip/hip_runtime.h>

#define B_ 64
#define LC 2048
#define LQ 256
#define DD 128

typedef __bf16 bf16;
typedef __bf16 bf16x8 __attribute__((ext_vector_type(8)));
typedef __bf16 bf16x4 __attribute__((ext_vector_type(4)));
typedef float f32x4 __attribute__((ext_vector_type(4)));

#define MFMA16(a, b, c) __builtin_amdgcn_mfma_f32_16x16x32_bf16((a), (b), (c), 0, 0, 0)

// Panel layouts (all bf16, chunk = 512 elems = 1KB, within-chunk: lr*32+lg*8+i):
//  Cwp  [b][cb  (LC/16)][ks 4 ][512]  elem (c=cb*16+lr, d=ks*32+lg*8+i) * w4mlu
//  Qbp  [b][qb  (LQ/16)][ks 4 ][512]  elem (q=qb*16+lr, d=ks*32+lg*8+i)
//  QbTp [b][ks  (LQ/32)][dt 8 ][512]  elem (d=dt*16+lr, q=ks*32+lg*8+i)
//  CbTp [b][cb32(LC/32)][d 128][32 ]  elem (c=cb32*32+ci, d)
//  Pp   [b][cb  (LC/16)][ks 8 ][512]  elem (c=cb*16+lr, q=ks*32+lg*8+i)
//  PTp  [b][qb  (LQ/16)][cks64][512]  elem (q=qb*16+lr, c=cks*32+lg*8+i)
//  MTpn [b][ks 8][dt 8][512]          elem (d=dt*16+lr, q=ks*32+lg*8+i)  (Linv folded)

// ---------------------------------------------------------------------------
// K1: prep C -> Cwp, CbTp, sub0, out block0 (exact fp32 C^T)
// grid (B*32), 256 thr; tile 64c x 128d; fp32 LDS
// ---------------------------------------------------------------------------
__global__ __launch_bounds__(256) void k_prep_c(const float* __restrict__ C,
    const float* __restrict__ w4C, const float* __restrict__ w4mlu,
    bf16* __restrict__ Cwp, bf16* __restrict__ CbTp,
    float* __restrict__ sub0, float* __restrict__ out)
{
    __shared__ float lds[64][DD + 4];
    int b = blockIdx.x >> 5, ct = blockIdx.x & 31;
    int c0 = ct * 64;
    int t = threadIdx.x;
    int r = t >> 2, cb = (t & 3) * 32;
    size_t rowoff = ((size_t)(b * LC + c0 + r)) * DD + cb;
    const float4* src = (const float4*)(C + rowoff);
    float s0 = 0.f;
#pragma unroll
    for (int i = 0; i < 8; ++i) {
        float4 v = src[i];
        int d = cb + i * 4;
        lds[r][d] = v.x; lds[r][d + 1] = v.y; lds[r][d + 2] = v.z; lds[r][d + 3] = v.w;
        s0 += v.x * w4C[d] + v.y * w4C[d + 1] + v.z * w4C[d + 2] + v.w * w4C[d + 3];
    }
    s0 += __shfl_xor(s0, 1);
    s0 += __shfl_xor(s0, 2);
    if ((t & 3) == 0) sub0[b * LC + c0 + r] = s0;
    __syncthreads();

    // Cwp panels: 16 chunks (cb_l 0..3, ks 0..3)
#pragma unroll
    for (int p = 0; p < 4; ++p) {
        int idx = p * 256 + t;
        int chunk = idx >> 6, w = idx & 63;
        int cb_l = chunk >> 2, ks = chunk & 3;
        int lr = w >> 2, lg = w & 3;
        int c_l = cb_l * 16 + lr, d0 = ks * 32 + lg * 8;
        bf16x8 v;
#pragma unroll
        for (int j = 0; j < 8; ++j) v[j] = (bf16)(lds[c_l][d0 + j] * w4mlu[d0 + j]);
        size_t off = ((size_t)((b * 128 + ct * 4 + cb_l) * 4 + ks)) * 512 + lr * 32 + lg * 8;
        *(bf16x8*)(Cwp + off) = v;
    }
    // CbTp panels: (cb32 0..1) x 128 d x 4 lg
#pragma unroll
    for (int p = 0; p < 4; ++p) {
        int idx = p * 256 + t;
        int cb32 = idx >> 9, rem = idx & 511;
        int d = rem >> 2, lg = rem & 3;
        int cl0 = cb32 * 32 + lg * 8;
        bf16x8 v;
#pragma unroll
        for (int j = 0; j < 8; ++j) v[j] = (bf16)lds[cl0 + j][d];
        size_t off = ((size_t)((b * 64 + ct * 2 + cb32) * 128 + d)) * 32 + lg * 8;
        *(bf16x8*)(CbTp + off) = v;
    }
    // out block 0: exact fp32 C^T, 256-B runs
#pragma unroll
    for (int p = 0; p < 8; ++p) {
        int d = p * 16 + (t >> 4);
        int cl = (t & 15) * 4;
        float4 v = {lds[cl][d], lds[cl + 1][d], lds[cl + 2][d], lds[cl + 3][d]};
        *(float4*)(out + ((size_t)(b * 512 + d)) * LC + c0 + cl) = v;
    }
}

// ---------------------------------------------------------------------------
// K2: prep Q -> Qbp, QbTp, sub1.  grid (B*4), 256 thr; tile 64q x 128d
// ---------------------------------------------------------------------------
__global__ __launch_bounds__(256) void k_prep_q(const float* __restrict__ Q,
    const float* __restrict__ w4Q, bf16* __restrict__ Qbp, bf16* __restrict__ QbTp,
    float* __restrict__ sub1)
{
    __shared__ bf16 lds[64][DD + 4];
    int b = blockIdx.x >> 2, qt = blockIdx.x & 3;
    int q0 = qt * 64;
    int t = threadIdx.x;
    int r = t >> 2, cb = (t & 3) * 32;
    size_t rowoff = ((size_t)(b * LQ + q0 + r)) * DD + cb;
    const float4* src = (const float4*)(Q + rowoff);
    float s1 = 0.f;
#pragma unroll
    for (int i = 0; i < 8; ++i) {
        float4 v = src[i];
        int d = cb + i * 4;
        lds[r][d] = (bf16)v.x; lds[r][d + 1] = (bf16)v.y;
        lds[r][d + 2] = (bf16)v.z; lds[r][d + 3] = (bf16)v.w;
        s1 += v.x * w4Q[d] + v.y * w4Q[d + 1] + v.z * w4Q[d + 2] + v.w * w4Q[d + 3];
    }
    s1 += __shfl_xor(s1, 1);
    s1 += __shfl_xor(s1, 2);
    if ((t & 3) == 0) sub1[b * LQ + q0 + r] = s1;
    __syncthreads();

    // Qbp: 16 chunks (qb_l 0..3, ks 0..3)
#pragma unroll
    for (int p = 0; p < 4; ++p) {
        int idx = p * 256 + t;
        int chunk = idx >> 6, w = idx & 63;
        int qb_l = chunk >> 2, ks = chunk & 3;
        int lr = w >> 2, lg = w & 3;
        bf16x8 v = *(bf16x8*)&lds[qb_l * 16 + lr][ks * 32 + lg * 8];
        size_t off = ((size_t)((b * 16 + qt * 4 + qb_l) * 4 + ks)) * 512 + lr * 32 + lg * 8;
        *(bf16x8*)(Qbp + off) = v;
    }
    // QbTp: 16 chunks (ks_l 0..1, dt 0..7), q-gather
#pragma unroll
    for (int p = 0; p < 4; ++p) {
        int idx = p * 256 + t;
        int chunk = idx >> 6, w = idx & 63;
        int ks_l = chunk >> 3, dt = chunk & 7;
        int lr = w >> 2, lg = w & 3;
        int d = dt * 16 + lr, ql = ks_l * 32 + lg * 8;
        bf16x8 v;
#pragma unroll
        for (int j = 0; j < 8; ++j) v[j] = lds[ql + j][d];
        size_t off = ((size_t)((b * 8 + qt * 2 + ks_l) * 8 + dt)) * 512 + lr * 32 + lg * 8;
        *(bf16x8*)(QbTp + off) = v;
    }
}

// ---------------------------------------------------------------------------
// K3: S = Cw@Qb^T + subs + bias; P = Qm*exp(S-8); panels Pp, PTp(=P*Cm);
//     Rpart rowsum partials, Lpart masked colsum partials.
// grid (16 ct, 4 qt, B), 256 thr (4 waves); block 128c x 64q
// ---------------------------------------------------------------------------
__global__ __launch_bounds__(256) void k_s(const bf16* __restrict__ Cwp,
    const bf16* __restrict__ Qbp, const float* __restrict__ sub0,
    const float* __restrict__ sub1, const float* __restrict__ Qmask,
    const float* __restrict__ Cmask, const float* __restrict__ bias,
    bf16* __restrict__ Pp, bf16* __restrict__ PTp,
    float* __restrict__ Rpart, float* __restrict__ Lpart)
{
    __shared__ bf16 ldsP[128][80];    // [c_local][q_local]
    __shared__ bf16 ldsPT[64][136];   // [q_local][c_local]
    int b = blockIdx.z, qt = blockIdx.y, ctile = blockIdx.x;
    int q0 = qt * 64;
    int t = threadIdx.x, wid = t >> 6, lane = t & 63;
    int lr = lane & 15, lg = lane >> 4;
    int rowbase = ctile * 128 + wid * 32;

    f32x4 acc[2][4];
#pragma unroll
    for (int rt = 0; rt < 2; ++rt)
#pragma unroll
        for (int ct = 0; ct < 4; ++ct) acc[rt][ct] = (f32x4){0.f, 0.f, 0.f, 0.f};

    const bf16* Ab = Cwp + ((size_t)((b * 128 + ctile * 8 + wid * 2) * 4)) * 512 + lr * 32 + lg * 8;
    const bf16* Bb = Qbp + ((size_t)((b * 16 + qt * 4) * 4)) * 512 + lr * 32 + lg * 8;
#pragma unroll
    for (int ks = 0; ks < 4; ++ks) {
        bf16x8 a0 = *(const bf16x8*)(Ab + (size_t)ks * 512);
        bf16x8 a1 = *(const bf16x8*)(Ab + (size_t)(4 + ks) * 512);
#pragma unroll
        for (int ct = 0; ct < 4; ++ct) {
            bf16x8 bb = *(const bf16x8*)(Bb + (size_t)(ct * 4 + ks) * 512);
            acc[0][ct] = MFMA16(a0, bb, acc[0][ct]);
            acc[1][ct] = MFMA16(a1, bb, acc[1][ct]);
        }
    }

    float biasv = bias[0];
    float sub0v[2][4], cmv[2][4];
#pragma unroll
    for (int rt = 0; rt < 2; ++rt)
#pragma unroll
        for (int j = 0; j < 4; ++j) {
            int idx = b * LC + rowbase + rt * 16 + lg * 4 + j;
            sub0v[rt][j] = sub0[idx];
            cmv[rt][j] = Cmask[idx];
        }

    float rsum[2][4] = {};
#pragma unroll
    for (int ct = 0; ct < 4; ++ct) {
        int q = q0 + ct * 16 + lr;
        float s1v = sub1[b * LQ + q] + biasv;
        float qm = Qmask[b * LQ + q];
        float colsum = 0.f;
#pragma unroll
        for (int rt = 0; rt < 2; ++rt) {
            bf16x4 ptv;
#pragma unroll
            for (int j = 0; j < 4; ++j) {
                float S = acc[rt][ct][j] + sub0v[rt][j] + s1v;
                float Pv = __expf(S - 8.0f) * qm;
                rsum[rt][j] += Pv;
                float pm = Pv * cmv[rt][j];
                colsum += pm;
                ptv[j] = (bf16)pm;
                ldsP[wid * 32 + rt * 16 + lg * 4 + j][ct * 16 + lr] = (bf16)Pv;
            }
            *(bf16x4*)&ldsPT[ct * 16 + lr][wid * 32 + rt * 16 + lg * 4] = ptv;
        }
        colsum += __shfl_xor(colsum, 16);
        colsum += __shfl_xor(colsum, 32);
        if (lg == 0)
            Lpart[((size_t)(b * 64 + ctile * 4 + wid)) * LQ + q] = colsum;
    }
#pragma unroll
    for (int rt = 0; rt < 2; ++rt)
#pragma unroll
        for (int j = 0; j < 4; ++j) {
            float s = rsum[rt][j];
            s += __shfl_xor(s, 1);
            s += __shfl_xor(s, 2);
            s += __shfl_xor(s, 4);
            s += __shfl_xor(s, 8);
            if (lr == 0)
                Rpart[((size_t)(b * 4 + qt)) * LC + rowbase + rt * 16 + lg * 4 + j] = s;
        }
    __syncthreads();

    // Pp panels: 16 chunks (cb_l 0..7, ks_l 0..1)
#pragma unroll
    for (int p = 0; p < 4; ++p) {
        int idx = p * 256 + t;
        int chunk = idx >> 6, w = idx & 63;
        int cb_l = chunk >> 1, ks_l = chunk & 1;
        int plr = w >> 2, plg = w & 3;
        bf16x8 v = *(bf16x8*)&ldsP[cb_l * 16 + plr][ks_l * 32 + plg * 8];
        size_t off = ((size_t)((b * 128 + ctile * 8 + cb_l) * 8 + qt * 2 + ks_l)) * 512
                     + plr * 32 + plg * 8;
        *(bf16x8*)(Pp + off) = v;
    }
    // PTp panels: 16 chunks (qb_l 0..3, cks_l 0..3)
#pragma unroll
    for (int p = 0; p < 4; ++p) {
        int idx = p * 256 + t;
        int chunk = idx >> 6, w = idx & 63;
        int qb_l = chunk >> 2, cks_l = chunk & 3;
        int plr = w >> 2, plg = w & 3;
        bf16x8 v = *(bf16x8*)&ldsPT[qb_l * 16 + plr][cks_l * 32 + plg * 8];
        size_t off = ((size_t)((b * 16 + qt * 4 + qb_l) * 64 + ctile * 4 + cks_l)) * 512
                     + plr * 32 + plg * 8;
        *(bf16x8*)(PTp + off) = v;
    }
}

// ---------------------------------------------------------------------------
// K4: K-split GEMM: MTp slice = sum over 256 c of CbT[d][c]*PT[q][c]
// grid (4 qt, 8 ksl, B), 256 thr; all loads contiguous 1KB; native-flat stores
// ---------------------------------------------------------------------------
__global__ __launch_bounds__(256) void k_m(const bf16* __restrict__ CbTp,
    const bf16* __restrict__ PTp, bf16* __restrict__ MTp)
{
    int b = blockIdx.z, ksl = blockIdx.y, qt = blockIdx.x;
    int t = threadIdx.x, wid = t >> 6, lane = t & 63;
    int lr = lane & 15, lg = lane >> 4;
    int dbase = wid * 32;

    f32x4 acc[2][4];
#pragma unroll
    for (int rt = 0; rt < 2; ++rt)
#pragma unroll
        for (int ct = 0; ct < 4; ++ct) acc[rt][ct] = (f32x4){0.f, 0.f, 0.f, 0.f};

    const bf16* Ab = CbTp + ((size_t)(b * 64 + ksl * 8) * 128 + dbase + lr) * 32 + lg * 8;
    const bf16* Bb = PTp + ((size_t)((b * 16 + qt * 4) * 64 + ksl * 8)) * 512 + lr * 32 + lg * 8;
#pragma unroll 2
    for (int ks = 0; ks < 8; ++ks) {
        bf16x8 a0 = *(const bf16x8*)(Ab + (size_t)ks * 4096);
        bf16x8 a1 = *(const bf16x8*)(Ab + (size_t)ks * 4096 + 16 * 32);
#pragma unroll
        for (int ct = 0; ct < 4; ++ct) {
            bf16x8 bb = *(const bf16x8*)(Bb + (size_t)(ct * 64 + ks) * 512);
            acc[0][ct] = MFMA16(a0, bb, acc[0][ct]);
            acc[1][ct] = MFMA16(a1, bb, acc[1][ct]);
        }
    }
    size_t base = ((((size_t)ksl * B_ + b) * 4 + qt) * 4 + wid) * 2048;
#pragma unroll
    for (int rt = 0; rt < 2; ++rt)
#pragma unroll
        for (int ct = 0; ct < 4; ++ct)
#pragma unroll
            for (int j = 0; j < 4; ++j)
                MTp[base + (size_t)(rt * 16 + ct * 4 + j) * 64 + lane] = (bf16)acc[rt][ct][j];
}

// ---------------------------------------------------------------------------
// K5: reduce 8 K-slices + fold Linv -> MTpn panel layout
// grid (4, B), 256 thr; vectorized slice reads (8 consecutive q per lane)
// ---------------------------------------------------------------------------
__global__ __launch_bounds__(256) void k_m2(const bf16* __restrict__ MTp,
    const float* __restrict__ Lpart, bf16* __restrict__ MTpn)
{
    __shared__ float ldsLinv[256];
    int b = blockIdx.y, ih = blockIdx.x;
    int t = threadIdx.x;
    {
        float s = 0.f;
#pragma unroll
        for (int sl = 0; sl < 64; ++sl) s += Lpart[((size_t)(b * 64 + sl)) * LQ + t];
        ldsLinv[t] = 1.0f / fmaxf(s, 1e-30f);
    }
    __syncthreads();
#pragma unroll
    for (int i = 0; i < 4; ++i) {
        int slot = (ih * 4 + i) * 256 + t;    // 0..4095
        int d = slot >> 5, qo = slot & 31;
        int q0 = qo * 8;
        int qt = q0 >> 6, ct = (q0 >> 4) & 3, lr0 = q0 & 15;
        int wid = d >> 5, rt = (d >> 4) & 1, lgd = (d >> 2) & 3, j = d & 3;
        size_t roff = ((size_t)(b * 4 + qt)) * 8192 + wid * 2048
                      + (rt * 16 + ct * 4 + j) * 64 + lgd * 16 + lr0;
        float a8[8] = {0.f, 0.f, 0.f, 0.f, 0.f, 0.f, 0.f, 0.f};
#pragma unroll
        for (int sl = 0; sl < 8; ++sl) {
            bf16x8 x = *(const bf16x8*)(MTp + (size_t)sl * B_ * 32768 + roff);
#pragma unroll
            for (int k = 0; k < 8; ++k) a8[k] += (float)x[k];
        }
        bf16x8 o;
#pragma unroll
        for (int k = 0; k < 8; ++k) o[k] = (bf16)(a8[k] * ldsLinv[q0 + k]);
        size_t woff = ((size_t)((b * 8 + (qo >> 2)) * 8 + (d >> 4))) * 512
                      + (d & 15) * 32 + (qo & 3) * 8;
        *(bf16x8*)(MTpn + woff) = o;
    }
}

// ---------------------------------------------------------------------------
// K6: A = Rinv*(P@Qb), Bt = Rinv*(P@M); bf16 LDS transpose, one barrier,
//     256-B-run fp32 stores of blocks 1..3; C read from out block 0 (fp32).
// grid (32 ctile, B), 256 thr (4 waves)
// ---------------------------------------------------------------------------
__global__ __launch_bounds__(256) void k_out(const bf16* __restrict__ Pp,
    const bf16* __restrict__ QbTp, const bf16* __restrict__ MTpn,
    const float* __restrict__ Rpart, float* __restrict__ out)
{
    __shared__ bf16 ldsA[DD][72];
    __shared__ bf16 ldsB[DD][72];
    int b = blockIdx.y, ctile = blockIdx.x;
    int t = threadIdx.x, wid = t >> 6, lane = t & 63;
    int lr = lane & 15, lg = lane >> 4;
    int c0 = ctile * 64;

    f32x4 accA[8], accB[8];
#pragma unroll
    for (int dt = 0; dt < 8; ++dt) {
        accA[dt] = (f32x4){0.f, 0.f, 0.f, 0.f};
        accB[dt] = (f32x4){0.f, 0.f, 0.f, 0.f};
    }
    const bf16* Ab = Pp + ((size_t)((b * 128 + ctile * 4 + wid) * 8)) * 512 + lr * 32 + lg * 8;
    const bf16* Qb = QbTp + ((size_t)(b * 8)) * 8 * 512 + lr * 32 + lg * 8;
    const bf16* Mb = MTpn + ((size_t)(b * 8)) * 8 * 512 + lr * 32 + lg * 8;
#pragma unroll
    for (int ks = 0; ks < 8; ++ks) {
        bf16x8 a = *(const bf16x8*)(Ab + (size_t)ks * 512);
#pragma unroll
        for (int dt = 0; dt < 8; ++dt) {
            bf16x8 bq = *(const bf16x8*)(Qb + (size_t)(ks * 8 + dt) * 512);
            bf16x8 bm = *(const bf16x8*)(Mb + (size_t)(ks * 8 + dt) * 512);
            accA[dt] = MFMA16(a, bq, accA[dt]);
            accB[dt] = MFMA16(a, bm, accB[dt]);
        }
    }
    f32x4 rs = (f32x4){0.f, 0.f, 0.f, 0.f};
#pragma unroll
    for (int s = 0; s < 4; ++s)
        rs += *(const f32x4*)(Rpart + ((size_t)(b * 4 + s)) * LC + c0 + wid * 16 + lg * 4);
    f32x4 rv;
#pragma unroll
    for (int j = 0; j < 4; ++j) rv[j] = 1.0f / fmaxf(rs[j], 1e-30f);

#pragma unroll
    for (int dt = 0; dt < 8; ++dt) {
        f32x4 a4 = accA[dt] * rv;
        f32x4 b4 = accB[dt] * rv;
        bf16x4 pa = { (bf16)a4[0], (bf16)a4[1], (bf16)a4[2], (bf16)a4[3] };
        bf16x4 pb = { (bf16)b4[0], (bf16)b4[1], (bf16)b4[2], (bf16)b4[3] };
        *(bf16x4*)&ldsA[dt * 16 + lr][wid * 16 + lg * 4] = pa;
        *(bf16x4*)&ldsB[dt * 16 + lr][wid * 16 + lg * 4] = pb;
    }
    __syncthreads();

    float* obase = out + ((size_t)b * 512) * LC;
#pragma unroll
    for (int pass = 0; pass < 8; ++pass) {
        int d = pass * 16 + (t >> 4);
        int cq = (t & 15) * 4;
        bf16x4 av = *(bf16x4*)&ldsA[d][cq];
        bf16x4 bv = *(bf16x4*)&ldsB[d][cq];
        float4 c4 = *(const float4*)(obase + (size_t)d * LC + c0 + cq);
        float4 a4 = {(float)av[0], (float)av[1], (float)av[2], (float)av[3]};
        float4 b4 = {(float)bv[0], (float)bv[1], (float)bv[2], (float)bv[3]};
        *(float4*)(obase + (size_t)(128 + d) * LC + c0 + cq) = a4;
        *(float4*)(obase + (size_t)(256 + d) * LC + c0 + cq) =
            (float4){c4.x * a4.x, c4.y * a4.y, c4.z * a4.z, c4.w * a4.w};
        *(float4*)(obase + (size_t)(384 + d) * LC + c0 + cq) =
            (float4){c4.x * b4.x, c4.y * b4.y, c4.z * b4.z, c4.w * b4.w};
    }
}

// ---------------------------------------------------------------------------
extern "C" void kernel_launch(void* const* d_in, const int* in_sizes, int n_in,
                              void* d_out, int out_size, void* d_ws, size_t ws_size,
                              hipStream_t stream)
{
    const float* C     = (const float*)d_in[0];
    const float* Q     = (const float*)d_in[1];
    const float* Cmask = (const float*)d_in[2];
    const float* Qmask = (const float*)d_in[3];
    const float* w4C   = (const float*)d_in[4];
    const float* w4Q   = (const float*)d_in[5];
    const float* w4mlu = (const float*)d_in[6];
    const float* bias  = (const float*)d_in[7];
    float* out = (float*)d_out;

    char* ws = (char*)d_ws;
    size_t off = 0;
    auto alloc = [&](size_t bytes) -> char* {
        char* p = ws + off;
        off += (bytes + 255) & ~(size_t)255;
        return p;
    };
    bf16* Cwp   = (bf16*)alloc((size_t)B_ * LC * DD * 2);
    bf16* CbTp  = (bf16*)alloc((size_t)B_ * LC * DD * 2);
    bf16* Qbp   = (bf16*)alloc((size_t)B_ * LQ * DD * 2);
    bf16* QbTp  = (bf16*)alloc((size_t)B_ * LQ * DD * 2);
    bf16* Pp    = (bf16*)alloc((size_t)B_ * LC * LQ * 2);
    bf16* PTp   = (bf16*)alloc((size_t)B_ * LC * LQ * 2);
    bf16* MTp   = (bf16*)alloc((size_t)8 * B_ * DD * LQ * 2);
    bf16* MTpn  = (bf16*)alloc((size_t)B_ * DD * LQ * 2);
    float* sub0 = (float*)alloc((size_t)B_ * LC * 4);
    float* sub1 = (float*)alloc((size_t)B_ * LQ * 4);
    float* Rpart = (float*)alloc((size_t)B_ * 4 * LC * 4);
    float* Lpart = (float*)alloc((size_t)B_ * 64 * LQ * 4);
    (void)ws_size; (void)in_sizes; (void)n_in; (void)out_size;

    hipLaunchKernelGGL(k_prep_c, dim3(B_ * 32), dim3(256), 0, stream,
                       C, w4C, w4mlu, Cwp, CbTp, sub0, out);
    hipLaunchKernelGGL(k_prep_q, dim3(B_ * 4), dim3(256), 0, stream,
                       Q, w4Q, Qbp, QbTp, sub1);
    hipLaunchKernelGGL(k_s, dim3(16, 4, B_), dim3(256), 0, stream,
                       Cwp, Qbp, sub0, sub1, Qmask, Cmask, bias, Pp, PTp, Rpart, Lpart);
    hipLaunchKernelGGL(k_m, dim3(4, 8, B_), dim3(256), 0, stream, CbTp, PTp, MTp);
    hipLaunchKernelGGL(k_m2, dim3(4, B_), dim3(256), 0, stream, MTp, Lpart, MTpn);
    hipLaunchKernelGGL(k_out, dim3(32, B_), dim3(256), 0, stream,
                       Pp, QbTp, MTpn, Rpart, out);
}

// Round 6
// 251.258 us; speedup vs baseline: 1.6647x; 1.2236x over previous
//
#include <hip/hip_runtime.h>

#define B_ 64
#define LC 2048
#define LQ 256
#define DD 128

typedef __bf16 bf16;
typedef __bf16 bf16x8 __attribute__((ext_vector_type(8)));
typedef __bf16 bf16x4 __attribute__((ext_vector_type(4)));
typedef float f32x4 __attribute__((ext_vector_type(4)));

#define MFMA16(a, b, c) __builtin_amdgcn_mfma_f32_16x16x32_bf16((a), (b), (c), 0, 0, 0)

// Panel layouts (all bf16, chunk = 512 elems = 1KB, within-chunk: lr*32+lg*8+i):
//  Cwp  [b][cb  (LC/16)][ks 4 ][512]  elem (c=cb*16+lr, d=ks*32+lg*8+i) * w4mlu
//  Qbp  [b][qb  (LQ/16)][ks 4 ][512]  elem (q=qb*16+lr, d=ks*32+lg*8+i)
//  QbTp [b][ks  (LQ/32)][dt 8 ][512]  elem (d=dt*16+lr, q=ks*32+lg*8+i)
//  CbTp [b][cb32(LC/32)][d 128][32 ]  elem (c=cb32*32+ci, d)
//  Pp   [b][cb  (LC/16)][ks 8 ][512]  elem (c=cb*16+lr, q=ks*32+lg*8+i)
//  PTp  [b][qb  (LQ/16)][cks64][512]  elem (q=qb*16+lr, c=cks*32+lg*8+i)
//  MTpn [b][ks 8][dt 8][512]          elem (d=dt*16+lr, q=ks*32+lg*8+i)  (Linv folded)

// ---------------------------------------------------------------------------
// K1: prep C -> Cwp, CbTp, sub0, out block0 (exact fp32 C^T)
// grid (B*32), 256 thr; tile 64c x 128d; fp32 LDS
// ---------------------------------------------------------------------------
__global__ __launch_bounds__(256) void k_prep_c(const float* __restrict__ C,
    const float* __restrict__ w4C, const float* __restrict__ w4mlu,
    bf16* __restrict__ Cwp, bf16* __restrict__ CbTp,
    float* __restrict__ sub0, float* __restrict__ out)
{
    __shared__ float lds[64][DD + 4];
    int b = blockIdx.x >> 5, ct = blockIdx.x & 31;
    int c0 = ct * 64;
    int t = threadIdx.x;
    int r = t >> 2, cb = (t & 3) * 32;
    size_t rowoff = ((size_t)(b * LC + c0 + r)) * DD + cb;
    const float4* src = (const float4*)(C + rowoff);
    float s0 = 0.f;
#pragma unroll
    for (int i = 0; i < 8; ++i) {
        float4 v = src[i];
        int d = cb + i * 4;
        lds[r][d] = v.x; lds[r][d + 1] = v.y; lds[r][d + 2] = v.z; lds[r][d + 3] = v.w;
        s0 += v.x * w4C[d] + v.y * w4C[d + 1] + v.z * w4C[d + 2] + v.w * w4C[d + 3];
    }
    s0 += __shfl_xor(s0, 1);
    s0 += __shfl_xor(s0, 2);
    if ((t & 3) == 0) sub0[b * LC + c0 + r] = s0;
    __syncthreads();

    // Cwp panels: 16 chunks (cb_l 0..3, ks 0..3)
#pragma unroll
    for (int p = 0; p < 4; ++p) {
        int idx = p * 256 + t;
        int chunk = idx >> 6, w = idx & 63;
        int cb_l = chunk >> 2, ks = chunk & 3;
        int lr = w >> 2, lg = w & 3;
        int c_l = cb_l * 16 + lr, d0 = ks * 32 + lg * 8;
        bf16x8 v;
#pragma unroll
        for (int j = 0; j < 8; ++j) v[j] = (bf16)(lds[c_l][d0 + j] * w4mlu[d0 + j]);
        size_t off = ((size_t)((b * 128 + ct * 4 + cb_l) * 4 + ks)) * 512 + lr * 32 + lg * 8;
        *(bf16x8*)(Cwp + off) = v;
    }
    // CbTp panels: (cb32 0..1) x 128 d x 4 lg
#pragma unroll
    for (int p = 0; p < 4; ++p) {
        int idx = p * 256 + t;
        int cb32 = idx >> 9, rem = idx & 511;
        int d = rem >> 2, lg = rem & 3;
        int cl0 = cb32 * 32 + lg * 8;
        bf16x8 v;
#pragma unroll
        for (int j = 0; j < 8; ++j) v[j] = (bf16)lds[cl0 + j][d];
        size_t off = ((size_t)((b * 64 + ct * 2 + cb32) * 128 + d)) * 32 + lg * 8;
        *(bf16x8*)(CbTp + off) = v;
    }
    // out block 0: exact fp32 C^T, 256-B runs
#pragma unroll
    for (int p = 0; p < 8; ++p) {
        int d = p * 16 + (t >> 4);
        int cl = (t & 15) * 4;
        float4 v = {lds[cl][d], lds[cl + 1][d], lds[cl + 2][d], lds[cl + 3][d]};
        *(float4*)(out + ((size_t)(b * 512 + d)) * LC + c0 + cl) = v;
    }
}

// ---------------------------------------------------------------------------
// K2: prep Q -> Qbp, QbTp, sub1.  grid (B*4), 256 thr; tile 64q x 128d
// ---------------------------------------------------------------------------
__global__ __launch_bounds__(256) void k_prep_q(const float* __restrict__ Q,
    const float* __restrict__ w4Q, bf16* __restrict__ Qbp, bf16* __restrict__ QbTp,
    float* __restrict__ sub1)
{
    __shared__ bf16 lds[64][DD + 4];
    int b = blockIdx.x >> 2, qt = blockIdx.x & 3;
    int q0 = qt * 64;
    int t = threadIdx.x;
    int r = t >> 2, cb = (t & 3) * 32;
    size_t rowoff = ((size_t)(b * LQ + q0 + r)) * DD + cb;
    const float4* src = (const float4*)(Q + rowoff);
    float s1 = 0.f;
#pragma unroll
    for (int i = 0; i < 8; ++i) {
        float4 v = src[i];
        int d = cb + i * 4;
        lds[r][d] = (bf16)v.x; lds[r][d + 1] = (bf16)v.y;
        lds[r][d + 2] = (bf16)v.z; lds[r][d + 3] = (bf16)v.w;
        s1 += v.x * w4Q[d] + v.y * w4Q[d + 1] + v.z * w4Q[d + 2] + v.w * w4Q[d + 3];
    }
    s1 += __shfl_xor(s1, 1);
    s1 += __shfl_xor(s1, 2);
    if ((t & 3) == 0) sub1[b * LQ + q0 + r] = s1;
    __syncthreads();

    // Qbp: 16 chunks (qb_l 0..3, ks 0..3)
#pragma unroll
    for (int p = 0; p < 4; ++p) {
        int idx = p * 256 + t;
        int chunk = idx >> 6, w = idx & 63;
        int qb_l = chunk >> 2, ks = chunk & 3;
        int lr = w >> 2, lg = w & 3;
        bf16x8 v = *(bf16x8*)&lds[qb_l * 16 + lr][ks * 32 + lg * 8];
        size_t off = ((size_t)((b * 16 + qt * 4 + qb_l) * 4 + ks)) * 512 + lr * 32 + lg * 8;
        *(bf16x8*)(Qbp + off) = v;
    }
    // QbTp: 16 chunks (ks_l 0..1, dt 0..7), q-gather
#pragma unroll
    for (int p = 0; p < 4; ++p) {
        int idx = p * 256 + t;
        int chunk = idx >> 6, w = idx & 63;
        int ks_l = chunk >> 3, dt = chunk & 7;
        int lr = w >> 2, lg = w & 3;
        int d = dt * 16 + lr, ql = ks_l * 32 + lg * 8;
        bf16x8 v;
#pragma unroll
        for (int j = 0; j < 8; ++j) v[j] = lds[ql + j][d];
        size_t off = ((size_t)((b * 8 + qt * 2 + ks_l) * 8 + dt)) * 512 + lr * 32 + lg * 8;
        *(bf16x8*)(QbTp + off) = v;
    }
}

// ---------------------------------------------------------------------------
// K3: S = Cw@Qb^T + subs + bias; P = Qm*exp(S-8); panels Pp, PTp(=P*Cm);
//     Rpart rowsum partials, Lpart masked colsum partials.
// grid (16 ct, 4 qt, B), 256 thr (4 waves); block 128c x 64q
// ---------------------------------------------------------------------------
__global__ __launch_bounds__(256) void k_s(const bf16* __restrict__ Cwp,
    const bf16* __restrict__ Qbp, const float* __restrict__ sub0,
    const float* __restrict__ sub1, const float* __restrict__ Qmask,
    const float* __restrict__ Cmask, const float* __restrict__ bias,
    bf16* __restrict__ Pp, bf16* __restrict__ PTp,
    float* __restrict__ Rpart, float* __restrict__ Lpart)
{
    __shared__ bf16 ldsP[128][80];    // [c_local][q_local]
    __shared__ bf16 ldsPT[64][136];   // [q_local][c_local]
    int b = blockIdx.z, qt = blockIdx.y, ctile = blockIdx.x;
    int q0 = qt * 64;
    int t = threadIdx.x, wid = t >> 6, lane = t & 63;
    int lr = lane & 15, lg = lane >> 4;
    int rowbase = ctile * 128 + wid * 32;

    f32x4 acc[2][4];
#pragma unroll
    for (int rt = 0; rt < 2; ++rt)
#pragma unroll
        for (int ct = 0; ct < 4; ++ct) acc[rt][ct] = (f32x4){0.f, 0.f, 0.f, 0.f};

    const bf16* Ab = Cwp + ((size_t)((b * 128 + ctile * 8 + wid * 2) * 4)) * 512 + lr * 32 + lg * 8;
    const bf16* Bb = Qbp + ((size_t)((b * 16 + qt * 4) * 4)) * 512 + lr * 32 + lg * 8;
#pragma unroll
    for (int ks = 0; ks < 4; ++ks) {
        bf16x8 a0 = *(const bf16x8*)(Ab + (size_t)ks * 512);
        bf16x8 a1 = *(const bf16x8*)(Ab + (size_t)(4 + ks) * 512);
#pragma unroll
        for (int ct = 0; ct < 4; ++ct) {
            bf16x8 bb = *(const bf16x8*)(Bb + (size_t)(ct * 4 + ks) * 512);
            acc[0][ct] = MFMA16(a0, bb, acc[0][ct]);
            acc[1][ct] = MFMA16(a1, bb, acc[1][ct]);
        }
    }

    float biasv = bias[0];
    float sub0v[2][4], cmv[2][4];
#pragma unroll
    for (int rt = 0; rt < 2; ++rt)
#pragma unroll
        for (int j = 0; j < 4; ++j) {
            int idx = b * LC + rowbase + rt * 16 + lg * 4 + j;
            sub0v[rt][j] = sub0[idx];
            cmv[rt][j] = Cmask[idx];
        }

    float rsum[2][4] = {};
#pragma unroll
    for (int ct = 0; ct < 4; ++ct) {
        int q = q0 + ct * 16 + lr;
        float s1v = sub1[b * LQ + q] + biasv;
        float qm = Qmask[b * LQ + q];
        float colsum = 0.f;
#pragma unroll
        for (int rt = 0; rt < 2; ++rt) {
            bf16x4 ptv;
#pragma unroll
            for (int j = 0; j < 4; ++j) {
                float S = acc[rt][ct][j] + sub0v[rt][j] + s1v;
                float Pv = __expf(S - 8.0f) * qm;
                rsum[rt][j] += Pv;
                float pm = Pv * cmv[rt][j];
                colsum += pm;
                ptv[j] = (bf16)pm;
                ldsP[wid * 32 + rt * 16 + lg * 4 + j][ct * 16 + lr] = (bf16)Pv;
            }
            *(bf16x4*)&ldsPT[ct * 16 + lr][wid * 32 + rt * 16 + lg * 4] = ptv;
        }
        colsum += __shfl_xor(colsum, 16);
        colsum += __shfl_xor(colsum, 32);
        if (lg == 0)
            Lpart[((size_t)(b * 64 + ctile * 4 + wid)) * LQ + q] = colsum;
    }
#pragma unroll
    for (int rt = 0; rt < 2; ++rt)
#pragma unroll
        for (int j = 0; j < 4; ++j) {
            float s = rsum[rt][j];
            s += __shfl_xor(s, 1);
            s += __shfl_xor(s, 2);
            s += __shfl_xor(s, 4);
            s += __shfl_xor(s, 8);
            if (lr == 0)
                Rpart[((size_t)(b * 4 + qt)) * LC + rowbase + rt * 16 + lg * 4 + j] = s;
        }
    __syncthreads();

    // Pp panels: 16 chunks (cb_l 0..7, ks_l 0..1)
#pragma unroll
    for (int p = 0; p < 4; ++p) {
        int idx = p * 256 + t;
        int chunk = idx >> 6, w = idx & 63;
        int cb_l = chunk >> 1, ks_l = chunk & 1;
        int plr = w >> 2, plg = w & 3;
        bf16x8 v = *(bf16x8*)&ldsP[cb_l * 16 + plr][ks_l * 32 + plg * 8];
        size_t off = ((size_t)((b * 128 + ctile * 8 + cb_l) * 8 + qt * 2 + ks_l)) * 512
                     + plr * 32 + plg * 8;
        *(bf16x8*)(Pp + off) = v;
    }
    // PTp panels: 16 chunks (qb_l 0..3, cks_l 0..3)
#pragma unroll
    for (int p = 0; p < 4; ++p) {
        int idx = p * 256 + t;
        int chunk = idx >> 6, w = idx & 63;
        int qb_l = chunk >> 2, cks_l = chunk & 3;
        int plr = w >> 2, plg = w & 3;
        bf16x8 v = *(bf16x8*)&ldsPT[qb_l * 16 + plr][cks_l * 32 + plg * 8];
        size_t off = ((size_t)((b * 16 + qt * 4 + qb_l) * 64 + ctile * 4 + cks_l)) * 512
                     + plr * 32 + plg * 8;
        *(bf16x8*)(PTp + off) = v;
    }
}

// ---------------------------------------------------------------------------
// K4: K-split GEMM: MTp slice = sum over 256 c of CbT[d][c]*PT[q][c]
// grid (4 qt, 8 ksl, B), 256 thr; all loads contiguous 1KB; native-flat stores
// ---------------------------------------------------------------------------
__global__ __launch_bounds__(256) void k_m(const bf16* __restrict__ CbTp,
    const bf16* __restrict__ PTp, bf16* __restrict__ MTp)
{
    int b = blockIdx.z, ksl = blockIdx.y, qt = blockIdx.x;
    int t = threadIdx.x, wid = t >> 6, lane = t & 63;
    int lr = lane & 15, lg = lane >> 4;
    int dbase = wid * 32;

    f32x4 acc[2][4];
#pragma unroll
    for (int rt = 0; rt < 2; ++rt)
#pragma unroll
        for (int ct = 0; ct < 4; ++ct) acc[rt][ct] = (f32x4){0.f, 0.f, 0.f, 0.f};

    const bf16* Ab = CbTp + ((size_t)(b * 64 + ksl * 8) * 128 + dbase + lr) * 32 + lg * 8;
    const bf16* Bb = PTp + ((size_t)((b * 16 + qt * 4) * 64 + ksl * 8)) * 512 + lr * 32 + lg * 8;
#pragma unroll 2
    for (int ks = 0; ks < 8; ++ks) {
        bf16x8 a0 = *(const bf16x8*)(Ab + (size_t)ks * 4096);
        bf16x8 a1 = *(const bf16x8*)(Ab + (size_t)ks * 4096 + 16 * 32);
#pragma unroll
        for (int ct = 0; ct < 4; ++ct) {
            bf16x8 bb = *(const bf16x8*)(Bb + (size_t)(ct * 64 + ks) * 512);
            acc[0][ct] = MFMA16(a0, bb, acc[0][ct]);
            acc[1][ct] = MFMA16(a1, bb, acc[1][ct]);
        }
    }
    size_t base = ((((size_t)ksl * B_ + b) * 4 + qt) * 4 + wid) * 2048;
#pragma unroll
    for (int rt = 0; rt < 2; ++rt)
#pragma unroll
        for (int ct = 0; ct < 4; ++ct)
#pragma unroll
            for (int j = 0; j < 4; ++j)
                MTp[base + (size_t)(rt * 16 + ct * 4 + j) * 64 + lane] = (bf16)acc[rt][ct][j];
}

// ---------------------------------------------------------------------------
// K5: reduce 8 K-slices + fold Linv -> MTpn panel layout
// grid (4, B), 256 thr; vectorized slice reads (8 consecutive q per lane)
// ---------------------------------------------------------------------------
__global__ __launch_bounds__(256) void k_m2(const bf16* __restrict__ MTp,
    const float* __restrict__ Lpart, bf16* __restrict__ MTpn)
{
    __shared__ float ldsLinv[256];
    int b = blockIdx.y, ih = blockIdx.x;
    int t = threadIdx.x;
    {
        float s = 0.f;
#pragma unroll
        for (int sl = 0; sl < 64; ++sl) s += Lpart[((size_t)(b * 64 + sl)) * LQ + t];
        ldsLinv[t] = 1.0f / fmaxf(s, 1e-30f);
    }
    __syncthreads();
#pragma unroll
    for (int i = 0; i < 4; ++i) {
        int slot = (ih * 4 + i) * 256 + t;    // 0..4095
        int d = slot >> 5, qo = slot & 31;
        int q0 = qo * 8;
        int qt = q0 >> 6, ct = (q0 >> 4) & 3, lr0 = q0 & 15;
        int wid = d >> 5, rt = (d >> 4) & 1, lgd = (d >> 2) & 3, j = d & 3;
        size_t roff = ((size_t)(b * 4 + qt)) * 8192 + wid * 2048
                      + (rt * 16 + ct * 4 + j) * 64 + lgd * 16 + lr0;
        float a8[8] = {0.f, 0.f, 0.f, 0.f, 0.f, 0.f, 0.f, 0.f};
#pragma unroll
        for (int sl = 0; sl < 8; ++sl) {
            bf16x8 x = *(const bf16x8*)(MTp + (size_t)sl * B_ * 32768 + roff);
#pragma unroll
            for (int k = 0; k < 8; ++k) a8[k] += (float)x[k];
        }
        bf16x8 o;
#pragma unroll
        for (int k = 0; k < 8; ++k) o[k] = (bf16)(a8[k] * ldsLinv[q0 + k]);
        size_t woff = ((size_t)((b * 8 + (qo >> 2)) * 8 + (d >> 4))) * 512
                      + (d & 15) * 32 + (qo & 3) * 8;
        *(bf16x8*)(MTpn + woff) = o;
    }
}

// ---------------------------------------------------------------------------
// K6: A = Rinv*(P@Qb), Bt = Rinv*(P@M).
//   2-phase pipeline: per-ks stage Q/M panels (16KB) into LDS double-buffer
//   (reg-staged; loads for ks+1 issued before ks's MFMAs, ds_write after).
//   B-frags from LDS -> 4x less L1 traffic, no per-MFMA VMEM dependency.
//   Epilogue transpose buffers UNION the staging LDS (total 36KB, 4 blk/CU).
// grid (32 ctile, B), 256 thr (4 waves)
// ---------------------------------------------------------------------------
__global__ __launch_bounds__(256) void k_out(const bf16* __restrict__ Pp,
    const bf16* __restrict__ QbTp, const bf16* __restrict__ MTpn,
    const float* __restrict__ Rpart, float* __restrict__ out)
{
    __shared__ f32x4 smem4[2304];                       // 36864 B
    bf16* stage = (bf16*)smem4;                         // stage[2][8192] elems (32 KB)
    bf16 (*ldsA)[72] = (bf16(*)[72])smem4;              // epilogue-only (union)
    bf16 (*ldsB)[72] = (bf16(*)[72])((char*)smem4 + 18432);

    int b = blockIdx.y, ctile = blockIdx.x;
    int t = threadIdx.x, wid = t >> 6, lane = t & 63;
    int lr = lane & 15, lg = lane >> 4;
    int c0 = ctile * 64;

    // staging: waves 0,1 -> Q panel (8KB), waves 2,3 -> M panel (8KB); 4KB/wave
    const bf16* gsrc = (wid < 2 ? QbTp : MTpn) + (size_t)b * 32768
                       + (size_t)(wid & 1) * 2048 + lane * 8;
    int ldst = wid * 2048 + lane * 8;   // elem offset within stage[buf]

    f32x4 accA[8], accB[8];
#pragma unroll
    for (int dt = 0; dt < 8; ++dt) {
        accA[dt] = (f32x4){0.f, 0.f, 0.f, 0.f};
        accB[dt] = (f32x4){0.f, 0.f, 0.f, 0.f};
    }
    const bf16* Ab = Pp + ((size_t)((b * 128 + ctile * 4 + wid) * 8)) * 512 + lr * 32 + lg * 8;

    // prologue: stage ks=0 into buf 0
    {
        bf16x8 g0 = *(const bf16x8*)(gsrc);
        bf16x8 g1 = *(const bf16x8*)(gsrc + 512);
        bf16x8 g2 = *(const bf16x8*)(gsrc + 1024);
        bf16x8 g3 = *(const bf16x8*)(gsrc + 1536);
        *(bf16x8*)&stage[ldst]        = g0;
        *(bf16x8*)&stage[ldst + 512]  = g1;
        *(bf16x8*)&stage[ldst + 1024] = g2;
        *(bf16x8*)&stage[ldst + 1536] = g3;
    }
    __syncthreads();

    for (int ks = 0; ks < 8; ++ks) {
        int cur = (ks & 1) * 8192;
        bf16x8 g0, g1, g2, g3;
        if (ks < 7) {
            const bf16* gs = gsrc + (size_t)(ks + 1) * 4096;
            g0 = *(const bf16x8*)(gs);
            g1 = *(const bf16x8*)(gs + 512);
            g2 = *(const bf16x8*)(gs + 1024);
            g3 = *(const bf16x8*)(gs + 1536);
        }
        bf16x8 a = *(const bf16x8*)(Ab + (size_t)ks * 512);
        int foff = cur + lr * 32 + lg * 8;
#pragma unroll
        for (int dt = 0; dt < 8; ++dt) {
            bf16x8 bq = *(bf16x8*)&stage[foff + dt * 512];
            bf16x8 bm = *(bf16x8*)&stage[foff + 4096 + dt * 512];
            accA[dt] = MFMA16(a, bq, accA[dt]);
            accB[dt] = MFMA16(a, bm, accB[dt]);
        }
        if (ks < 7) {
            int nb = cur ^ 8192;
            *(bf16x8*)&stage[nb + ldst]        = g0;
            *(bf16x8*)&stage[nb + ldst + 512]  = g1;
            *(bf16x8*)&stage[nb + ldst + 1024] = g2;
            *(bf16x8*)&stage[nb + ldst + 1536] = g3;
        }
        __syncthreads();
    }

    f32x4 rs = (f32x4){0.f, 0.f, 0.f, 0.f};
#pragma unroll
    for (int s = 0; s < 4; ++s)
        rs += *(const f32x4*)(Rpart + ((size_t)(b * 4 + s)) * LC + c0 + wid * 16 + lg * 4);
    f32x4 rv;
#pragma unroll
    for (int j = 0; j < 4; ++j) rv[j] = 1.0f / fmaxf(rs[j], 1e-30f);

    // epilogue: pack scaled accs into (unioned) transpose buffers
#pragma unroll
    for (int dt = 0; dt < 8; ++dt) {
        f32x4 a4 = accA[dt] * rv;
        f32x4 b4 = accB[dt] * rv;
        bf16x4 pa = { (bf16)a4[0], (bf16)a4[1], (bf16)a4[2], (bf16)a4[3] };
        bf16x4 pb = { (bf16)b4[0], (bf16)b4[1], (bf16)b4[2], (bf16)b4[3] };
        *(bf16x4*)&ldsA[dt * 16 + lr][wid * 16 + lg * 4] = pa;
        *(bf16x4*)&ldsB[dt * 16 + lr][wid * 16 + lg * 4] = pb;
    }
    __syncthreads();

    float* obase = out + ((size_t)b * 512) * LC;
#pragma unroll
    for (int pass = 0; pass < 8; ++pass) {
        int d = pass * 16 + (t >> 4);
        int cq = (t & 15) * 4;
        bf16x4 av = *(bf16x4*)&ldsA[d][cq];
        bf16x4 bv = *(bf16x4*)&ldsB[d][cq];
        float4 c4 = *(const float4*)(obase + (size_t)d * LC + c0 + cq);
        float4 a4 = {(float)av[0], (float)av[1], (float)av[2], (float)av[3]};
        float4 b4 = {(float)bv[0], (float)bv[1], (float)bv[2], (float)bv[3]};
        *(float4*)(obase + (size_t)(128 + d) * LC + c0 + cq) = a4;
        *(float4*)(obase + (size_t)(256 + d) * LC + c0 + cq) =
            (float4){c4.x * a4.x, c4.y * a4.y, c4.z * a4.z, c4.w * a4.w};
        *(float4*)(obase + (size_t)(384 + d) * LC + c0 + cq) =
            (float4){c4.x * b4.x, c4.y * b4.y, c4.z * b4.z, c4.w * b4.w};
    }
}

// ---------------------------------------------------------------------------
extern "C" void kernel_launch(void* const* d_in, const int* in_sizes, int n_in,
                              void* d_out, int out_size, void* d_ws, size_t ws_size,
                              hipStream_t stream)
{
    const float* C     = (const float*)d_in[0];
    const float* Q     = (const float*)d_in[1];
    const float* Cmask = (const float*)d_in[2];
    const float* Qmask = (const float*)d_in[3];
    const float* w4C   = (const float*)d_in[4];
    const float* w4Q   = (const float*)d_in[5];
    const float* w4mlu = (const float*)d_in[6];
    const float* bias  = (const float*)d_in[7];
    float* out = (float*)d_out;

    char* ws = (char*)d_ws;
    size_t off = 0;
    auto alloc = [&](size_t bytes) -> char* {
        char* p = ws + off;
        off += (bytes + 255) & ~(size_t)255;
        return p;
    };
    bf16* Cwp   = (bf16*)alloc((size_t)B_ * LC * DD * 2);
    bf16* CbTp  = (bf16*)alloc((size_t)B_ * LC * DD * 2);
    bf16* Qbp   = (bf16*)alloc((size_t)B_ * LQ * DD * 2);
    bf16* QbTp  = (bf16*)alloc((size_t)B_ * LQ * DD * 2);
    bf16* Pp    = (bf16*)alloc((size_t)B_ * LC * LQ * 2);
    bf16* PTp   = (bf16*)alloc((size_t)B_ * LC * LQ * 2);
    bf16* MTp   = (bf16*)alloc((size_t)8 * B_ * DD * LQ * 2);
    bf16* MTpn  = (bf16*)alloc((size_t)B_ * DD * LQ * 2);
    float* sub0 = (float*)alloc((size_t)B_ * LC * 4);
    float* sub1 = (float*)alloc((size_t)B_ * LQ * 4);
    float* Rpart = (float*)alloc((size_t)B_ * 4 * LC * 4);
    float* Lpart = (float*)alloc((size_t)B_ * 64 * LQ * 4);
    (void)ws_size; (void)in_sizes; (void)n_in; (void)out_size;

    hipLaunchKernelGGL(k_prep_c, dim3(B_ * 32), dim3(256), 0, stream,
                       C, w4C, w4mlu, Cwp, CbTp, sub0, out);
    hipLaunchKernelGGL(k_prep_q, dim3(B_ * 4), dim3(256), 0, stream,
                       Q, w4Q, Qbp, QbTp, sub1);
    hipLaunchKernelGGL(k_s, dim3(16, 4, B_), dim3(256), 0, stream,
                       Cwp, Qbp, sub0, sub1, Qmask, Cmask, bias, Pp, PTp, Rpart, Lpart);
    hipLaunchKernelGGL(k_m, dim3(4, 8, B_), dim3(256), 0, stream, CbTp, PTp, MTp);
    hipLaunchKernelGGL(k_m2, dim3(4, B_), dim3(256), 0, stream, MTp, Lpart, MTpn);
    hipLaunchKernelGGL(k_out, dim3(32, B_), dim3(256), 0, stream,
                       Pp, QbTp, MTpn, Rpart, out);
}

// Round 7
// 233.316 us; speedup vs baseline: 1.7927x; 1.0769x over previous
//
#include <hip/hip_runtime.h>

#define B_ 64
#define LC 2048
#define LQ 256
#define DD 128

typedef __bf16 bf16;
typedef __bf16 bf16x8 __attribute__((ext_vector_type(8)));
typedef __bf16 bf16x4 __attribute__((ext_vector_type(4)));
typedef float f32x4 __attribute__((ext_vector_type(4)));

#define MFMA16(a, b, c) __builtin_amdgcn_mfma_f32_16x16x32_bf16((a), (b), (c), 0, 0, 0)

// Panel layouts (bf16, chunk = 512 elems = 1KB).
// NEW within-chunk order is LANE-LINEAR: fragment for MFMA-lane l=(lg*16+lr)
// sits at elems [l*8 .. l*8+7]  ->  LDS reads at lane*16B are conflict-free.
//  Cwp  [b][cb  (LC/16)][ks 4 ][512]  frag(lr,lg): c=cb*16+lr, d=ks*32+lg*8+i
//  Qbp  [b][qb  (LQ/16)][ks 4 ][512]  frag(lr,lg): q=qb*16+lr, d=ks*32+lg*8+i
//  QbTp [b][ks  (LQ/32)][dt 8 ][512]  frag(lr,lg): d=dt*16+lr, q=ks*32+lg*8+i
//  CbTp [b][cb32(LC/32)][d 128][32 ]  elem (c=cb32*32+ci, d)   (unchanged)
//  Pp   [b][cb  (LC/16)][ks 8 ][512]  frag(lr,lg): c=cb*16+lr, q=ks*32+lg*8+i
//  PTp  [b][qb  (LQ/16)][cks64][512]  frag(lr,lg): q=qb*16+lr, c=cks*32+lg*8+i
//  MTpn [b][ks 8][dt 8][512]          frag(lr,lg): d=dt*16+lr, q=ks*32+lg*8+i (Linv folded)

// ---------------------------------------------------------------------------
// K1: prep C -> Cwp, CbTp, sub0, out block0 (exact fp32 C^T)
// ---------------------------------------------------------------------------
__global__ __launch_bounds__(256) void k_prep_c(const float* __restrict__ C,
    const float* __restrict__ w4C, const float* __restrict__ w4mlu,
    bf16* __restrict__ Cwp, bf16* __restrict__ CbTp,
    float* __restrict__ sub0, float* __restrict__ out)
{
    __shared__ float lds[64][DD + 4];
    int b = blockIdx.x >> 5, ct = blockIdx.x & 31;
    int c0 = ct * 64;
    int t = threadIdx.x;
    int r = t >> 2, cb = (t & 3) * 32;
    size_t rowoff = ((size_t)(b * LC + c0 + r)) * DD + cb;
    const float4* src = (const float4*)(C + rowoff);
    float s0 = 0.f;
#pragma unroll
    for (int i = 0; i < 8; ++i) {
        float4 v = src[i];
        int d = cb + i * 4;
        lds[r][d] = v.x; lds[r][d + 1] = v.y; lds[r][d + 2] = v.z; lds[r][d + 3] = v.w;
        s0 += v.x * w4C[d] + v.y * w4C[d + 1] + v.z * w4C[d + 2] + v.w * w4C[d + 3];
    }
    s0 += __shfl_xor(s0, 1);
    s0 += __shfl_xor(s0, 2);
    if ((t & 3) == 0) sub0[b * LC + c0 + r] = s0;
    __syncthreads();

    // Cwp panels: 16 chunks (cb_l 0..3, ks 0..3), lane-linear
#pragma unroll
    for (int p = 0; p < 4; ++p) {
        int idx = p * 256 + t;
        int chunk = idx >> 6, w = idx & 63;
        int cb_l = chunk >> 2, ks = chunk & 3;
        int lr = w & 15, lg = w >> 4;
        int c_l = cb_l * 16 + lr, d0 = ks * 32 + lg * 8;
        bf16x8 v;
#pragma unroll
        for (int j = 0; j < 8; ++j) v[j] = (bf16)(lds[c_l][d0 + j] * w4mlu[d0 + j]);
        size_t off = ((size_t)((b * 128 + ct * 4 + cb_l) * 4 + ks)) * 512 + w * 8;
        *(bf16x8*)(Cwp + off) = v;
    }
    // CbTp panels (layout unchanged)
#pragma unroll
    for (int p = 0; p < 4; ++p) {
        int idx = p * 256 + t;
        int cb32 = idx >> 9, rem = idx & 511;
        int d = rem >> 2, lg = rem & 3;
        int cl0 = cb32 * 32 + lg * 8;
        bf16x8 v;
#pragma unroll
        for (int j = 0; j < 8; ++j) v[j] = (bf16)lds[cl0 + j][d];
        size_t off = ((size_t)((b * 64 + ct * 2 + cb32) * 128 + d)) * 32 + lg * 8;
        *(bf16x8*)(CbTp + off) = v;
    }
    // out block 0: exact fp32 C^T, 256-B runs
#pragma unroll
    for (int p = 0; p < 8; ++p) {
        int d = p * 16 + (t >> 4);
        int cl = (t & 15) * 4;
        float4 v = {lds[cl][d], lds[cl + 1][d], lds[cl + 2][d], lds[cl + 3][d]};
        *(float4*)(out + ((size_t)(b * 512 + d)) * LC + c0 + cl) = v;
    }
}

// ---------------------------------------------------------------------------
// K2: prep Q -> Qbp, QbTp, sub1
// ---------------------------------------------------------------------------
__global__ __launch_bounds__(256) void k_prep_q(const float* __restrict__ Q,
    const float* __restrict__ w4Q, bf16* __restrict__ Qbp, bf16* __restrict__ QbTp,
    float* __restrict__ sub1)
{
    __shared__ bf16 lds[64][DD + 4];
    int b = blockIdx.x >> 2, qt = blockIdx.x & 3;
    int q0 = qt * 64;
    int t = threadIdx.x;
    int r = t >> 2, cb = (t & 3) * 32;
    size_t rowoff = ((size_t)(b * LQ + q0 + r)) * DD + cb;
    const float4* src = (const float4*)(Q + rowoff);
    float s1 = 0.f;
#pragma unroll
    for (int i = 0; i < 8; ++i) {
        float4 v = src[i];
        int d = cb + i * 4;
        lds[r][d] = (bf16)v.x; lds[r][d + 1] = (bf16)v.y;
        lds[r][d + 2] = (bf16)v.z; lds[r][d + 3] = (bf16)v.w;
        s1 += v.x * w4Q[d] + v.y * w4Q[d + 1] + v.z * w4Q[d + 2] + v.w * w4Q[d + 3];
    }
    s1 += __shfl_xor(s1, 1);
    s1 += __shfl_xor(s1, 2);
    if ((t & 3) == 0) sub1[b * LQ + q0 + r] = s1;
    __syncthreads();

    // Qbp: lane-linear chunks
#pragma unroll
    for (int p = 0; p < 4; ++p) {
        int idx = p * 256 + t;
        int chunk = idx >> 6, w = idx & 63;
        int qb_l = chunk >> 2, ks = chunk & 3;
        int lr = w & 15, lg = w >> 4;
        bf16x8 v = *(bf16x8*)&lds[qb_l * 16 + lr][ks * 32 + lg * 8];
        size_t off = ((size_t)((b * 16 + qt * 4 + qb_l) * 4 + ks)) * 512 + w * 8;
        *(bf16x8*)(Qbp + off) = v;
    }
    // QbTp: lane-linear chunks, q-gather
#pragma unroll
    for (int p = 0; p < 4; ++p) {
        int idx = p * 256 + t;
        int chunk = idx >> 6, w = idx & 63;
        int ks_l = chunk >> 3, dt = chunk & 7;
        int lr = w & 15, lg = w >> 4;
        int d = dt * 16 + lr, ql = ks_l * 32 + lg * 8;
        bf16x8 v;
#pragma unroll
        for (int j = 0; j < 8; ++j) v[j] = lds[ql + j][d];
        size_t off = ((size_t)((b * 8 + qt * 2 + ks_l) * 8 + dt)) * 512 + w * 8;
        *(bf16x8*)(QbTp + off) = v;
    }
}

// ---------------------------------------------------------------------------
// K3: S = Cw@Qb^T + subs + bias; P = Qm*exp(S-8); panels Pp, PTp(=P*Cm);
//     Rpart rowsum partials, Lpart masked colsum partials.
// grid (16 ct, 4 qt, B), 256 thr (4 waves); block 128c x 64q
// ---------------------------------------------------------------------------
__global__ __launch_bounds__(256) void k_s(const bf16* __restrict__ Cwp,
    const bf16* __restrict__ Qbp, const float* __restrict__ sub0,
    const float* __restrict__ sub1, const float* __restrict__ Qmask,
    const float* __restrict__ Cmask, const float* __restrict__ bias,
    bf16* __restrict__ Pp, bf16* __restrict__ PTp,
    float* __restrict__ Rpart, float* __restrict__ Lpart)
{
    __shared__ bf16 ldsP[128][80];    // [c_local][q_local]
    __shared__ bf16 ldsPT[64][136];   // [q_local][c_local]
    int b = blockIdx.z, qt = blockIdx.y, ctile = blockIdx.x;
    int q0 = qt * 64;
    int t = threadIdx.x, wid = t >> 6, lane = t & 63;
    int lr = lane & 15, lg = lane >> 4;
    int rowbase = ctile * 128 + wid * 32;

    f32x4 acc[2][4];
#pragma unroll
    for (int rt = 0; rt < 2; ++rt)
#pragma unroll
        for (int ct = 0; ct < 4; ++ct) acc[rt][ct] = (f32x4){0.f, 0.f, 0.f, 0.f};

    const bf16* Ab = Cwp + ((size_t)((b * 128 + ctile * 8 + wid * 2) * 4)) * 512 + lane * 8;
    const bf16* Bb = Qbp + ((size_t)((b * 16 + qt * 4) * 4)) * 512 + lane * 8;
#pragma unroll
    for (int ks = 0; ks < 4; ++ks) {
        bf16x8 a0 = *(const bf16x8*)(Ab + (size_t)ks * 512);
        bf16x8 a1 = *(const bf16x8*)(Ab + (size_t)(4 + ks) * 512);
#pragma unroll
        for (int ct = 0; ct < 4; ++ct) {
            bf16x8 bb = *(const bf16x8*)(Bb + (size_t)(ct * 4 + ks) * 512);
            acc[0][ct] = MFMA16(a0, bb, acc[0][ct]);
            acc[1][ct] = MFMA16(a1, bb, acc[1][ct]);
        }
    }

    float biasv = bias[0];
    float sub0v[2][4], cmv[2][4];
#pragma unroll
    for (int rt = 0; rt < 2; ++rt)
#pragma unroll
        for (int j = 0; j < 4; ++j) {
            int idx = b * LC + rowbase + rt * 16 + lg * 4 + j;
            sub0v[rt][j] = sub0[idx];
            cmv[rt][j] = Cmask[idx];
        }

    float rsum[2][4] = {};
#pragma unroll
    for (int ct = 0; ct < 4; ++ct) {
        int q = q0 + ct * 16 + lr;
        float s1v = sub1[b * LQ + q] + biasv;
        float qm = Qmask[b * LQ + q];
        float colsum = 0.f;
#pragma unroll
        for (int rt = 0; rt < 2; ++rt) {
            bf16x4 ptv;
#pragma unroll
            for (int j = 0; j < 4; ++j) {
                float S = acc[rt][ct][j] + sub0v[rt][j] + s1v;
                float Pv = __expf(S - 8.0f) * qm;
                rsum[rt][j] += Pv;
                float pm = Pv * cmv[rt][j];
                colsum += pm;
                ptv[j] = (bf16)pm;
                ldsP[wid * 32 + rt * 16 + lg * 4 + j][ct * 16 + lr] = (bf16)Pv;
            }
            *(bf16x4*)&ldsPT[ct * 16 + lr][wid * 32 + rt * 16 + lg * 4] = ptv;
        }
        colsum += __shfl_xor(colsum, 16);
        colsum += __shfl_xor(colsum, 32);
        if (lg == 0)
            Lpart[((size_t)(b * 64 + ctile * 4 + wid)) * LQ + q] = colsum;
    }
#pragma unroll
    for (int rt = 0; rt < 2; ++rt)
#pragma unroll
        for (int j = 0; j < 4; ++j) {
            float s = rsum[rt][j];
            s += __shfl_xor(s, 1);
            s += __shfl_xor(s, 2);
            s += __shfl_xor(s, 4);
            s += __shfl_xor(s, 8);
            if (lr == 0)
                Rpart[((size_t)(b * 4 + qt)) * LC + rowbase + rt * 16 + lg * 4 + j] = s;
        }
    __syncthreads();

    // Pp panels: 16 chunks (cb_l 0..7, ks_l 0..1), lane-linear
#pragma unroll
    for (int p = 0; p < 4; ++p) {
        int idx = p * 256 + t;
        int chunk = idx >> 6, w = idx & 63;
        int cb_l = chunk >> 1, ks_l = chunk & 1;
        int plr = w & 15, plg = w >> 4;
        bf16x8 v = *(bf16x8*)&ldsP[cb_l * 16 + plr][ks_l * 32 + plg * 8];
        size_t off = ((size_t)((b * 128 + ctile * 8 + cb_l) * 8 + qt * 2 + ks_l)) * 512 + w * 8;
        *(bf16x8*)(Pp + off) = v;
    }
    // PTp panels: 16 chunks (qb_l 0..3, cks_l 0..3), lane-linear
#pragma unroll
    for (int p = 0; p < 4; ++p) {
        int idx = p * 256 + t;
        int chunk = idx >> 6, w = idx & 63;
        int qb_l = chunk >> 2, cks_l = chunk & 3;
        int plr = w & 15, plg = w >> 4;
        bf16x8 v = *(bf16x8*)&ldsPT[qb_l * 16 + plr][cks_l * 32 + plg * 8];
        size_t off = ((size_t)((b * 16 + qt * 4 + qb_l) * 64 + ctile * 4 + cks_l)) * 512 + w * 8;
        *(bf16x8*)(PTp + off) = v;
    }
}

// ---------------------------------------------------------------------------
// K4: K-split GEMM: MTp slice = sum over 256 c of CbT[d][c]*PT[q][c]
//   2-phase reg-staged LDS dbuf for the (wave-shared) B panels: 4KB/iter,
//   one barrier/iter; lane-linear chunks -> conflict-free ds_read_b128.
// grid (4 qt, 8 ksl, B), 256 thr
// ---------------------------------------------------------------------------
__global__ __launch_bounds__(256) void k_m(const bf16* __restrict__ CbTp,
    const bf16* __restrict__ PTp, bf16* __restrict__ MTp)
{
    __shared__ bf16 stage[2 * 2048];   // 8 KB
    int b = blockIdx.z, ksl = blockIdx.y, qt = blockIdx.x;
    int t = threadIdx.x, wid = t >> 6, lane = t & 63;
    int lr = lane & 15, lg = lane >> 4;
    int dbase = wid * 32;

    f32x4 acc[2][4];
#pragma unroll
    for (int rt = 0; rt < 2; ++rt)
#pragma unroll
        for (int ct = 0; ct < 4; ++ct) acc[rt][ct] = (f32x4){0.f, 0.f, 0.f, 0.f};

    const bf16* Ab = CbTp + ((size_t)(b * 64 + ksl * 8) * 128 + dbase + lr) * 32 + lg * 8;
    // thread t stages chunk ct=wid, frag-slot lane (1KB/chunk, 4 chunks/iter)
    const bf16* Bsrc = PTp + ((size_t)((b * 16 + qt * 4 + wid) * 64 + ksl * 8)) * 512 + lane * 8;
    int ldst = wid * 512 + lane * 8;

    *(bf16x8*)&stage[ldst] = *(const bf16x8*)(Bsrc);
    __syncthreads();

    for (int ks = 0; ks < 8; ++ks) {
        int cur = (ks & 1) * 2048;
        bf16x8 g;
        if (ks < 7) g = *(const bf16x8*)(Bsrc + (size_t)(ks + 1) * 512);
        bf16x8 a0 = *(const bf16x8*)(Ab + (size_t)ks * 4096);
        bf16x8 a1 = *(const bf16x8*)(Ab + (size_t)ks * 4096 + 512);
#pragma unroll
        for (int ct = 0; ct < 4; ++ct) {
            bf16x8 bb = *(bf16x8*)&stage[cur + ct * 512 + lane * 8];
            acc[0][ct] = MFMA16(a0, bb, acc[0][ct]);
            acc[1][ct] = MFMA16(a1, bb, acc[1][ct]);
        }
        if (ks < 7) *(bf16x8*)&stage[(cur ^ 2048) + ldst] = g;
        __syncthreads();
    }

    size_t base = ((((size_t)ksl * B_ + b) * 4 + qt) * 4 + wid) * 2048;
#pragma unroll
    for (int rt = 0; rt < 2; ++rt)
#pragma unroll
        for (int ct = 0; ct < 4; ++ct)
#pragma unroll
            for (int j = 0; j < 4; ++j)
                MTp[base + (size_t)(rt * 16 + ct * 4 + j) * 64 + lane] = (bf16)acc[rt][ct][j];
}

// ---------------------------------------------------------------------------
// K5: reduce 8 K-slices + fold Linv -> MTpn (lane-linear chunks)
// grid (4, B), 256 thr
// ---------------------------------------------------------------------------
__global__ __launch_bounds__(256) void k_m2(const bf16* __restrict__ MTp,
    const float* __restrict__ Lpart, bf16* __restrict__ MTpn)
{
    __shared__ float ldsLinv[256];
    int b = blockIdx.y, ih = blockIdx.x;
    int t = threadIdx.x;
    {
        float s = 0.f;
#pragma unroll
        for (int sl = 0; sl < 64; ++sl) s += Lpart[((size_t)(b * 64 + sl)) * LQ + t];
        ldsLinv[t] = 1.0f / fmaxf(s, 1e-30f);
    }
    __syncthreads();
#pragma unroll
    for (int i = 0; i < 4; ++i) {
        int slot = (ih * 4 + i) * 256 + t;    // 0..4095
        int d = slot >> 5, qo = slot & 31;
        int q0 = qo * 8;
        int qt = q0 >> 6, ct = (q0 >> 4) & 3, lr0 = q0 & 15;
        int wid = d >> 5, rt = (d >> 4) & 1, lgd = (d >> 2) & 3, j = d & 3;
        size_t roff = ((size_t)(b * 4 + qt)) * 8192 + wid * 2048
                      + (rt * 16 + ct * 4 + j) * 64 + lgd * 16 + lr0;
        float a8[8] = {0.f, 0.f, 0.f, 0.f, 0.f, 0.f, 0.f, 0.f};
#pragma unroll
        for (int sl = 0; sl < 8; ++sl) {
            bf16x8 x = *(const bf16x8*)(MTp + (size_t)sl * B_ * 32768 + roff);
#pragma unroll
            for (int k = 0; k < 8; ++k) a8[k] += (float)x[k];
        }
        bf16x8 o;
#pragma unroll
        for (int k = 0; k < 8; ++k) o[k] = (bf16)(a8[k] * ldsLinv[q0 + k]);
        size_t woff = ((size_t)((b * 8 + (qo >> 2)) * 8 + (d >> 4))) * 512
                      + ((qo & 3) * 16 + (d & 15)) * 8;
        *(bf16x8*)(MTpn + woff) = o;
    }
}

// ---------------------------------------------------------------------------
// K6: A = Rinv*(P@Qb), Bt = Rinv*(P@M).
//   2-phase reg-staged LDS dbuf of Q/M panels (16KB/iter-pair), lane-linear
//   chunks -> conflict-free stage reads. Epilogue unions transpose buffers.
//   C for C*A / C*Bt read from CbTp (bf16, half the bytes of fp32 block0).
// grid (32 ctile, B), 256 thr (4 waves)
// ---------------------------------------------------------------------------
__global__ __launch_bounds__(256) void k_out(const bf16* __restrict__ Pp,
    const bf16* __restrict__ QbTp, const bf16* __restrict__ MTpn,
    const bf16* __restrict__ CbTp, const float* __restrict__ Rpart,
    float* __restrict__ out)
{
    __shared__ f32x4 smem4[2304];                       // 36864 B
    bf16* stage = (bf16*)smem4;                         // stage[2][8192] (32 KB)
    bf16 (*ldsA)[72] = (bf16(*)[72])smem4;              // epilogue-only (union)
    bf16 (*ldsB)[72] = (bf16(*)[72])((char*)smem4 + 18432);

    int b = blockIdx.y, ctile = blockIdx.x;
    int t = threadIdx.x, wid = t >> 6, lane = t & 63;
    int lr = lane & 15, lg = lane >> 4;
    int c0 = ctile * 64;

    const bf16* gsrc = (wid < 2 ? QbTp : MTpn) + (size_t)b * 32768
                       + (size_t)(wid & 1) * 2048 + lane * 8;
    int ldst = wid * 2048 + lane * 8;

    f32x4 accA[8], accB[8];
#pragma unroll
    for (int dt = 0; dt < 8; ++dt) {
        accA[dt] = (f32x4){0.f, 0.f, 0.f, 0.f};
        accB[dt] = (f32x4){0.f, 0.f, 0.f, 0.f};
    }
    const bf16* Ab = Pp + ((size_t)((b * 128 + ctile * 4 + wid) * 8)) * 512 + lane * 8;

    {
        bf16x8 g0 = *(const bf16x8*)(gsrc);
        bf16x8 g1 = *(const bf16x8*)(gsrc + 512);
        bf16x8 g2 = *(const bf16x8*)(gsrc + 1024);
        bf16x8 g3 = *(const bf16x8*)(gsrc + 1536);
        *(bf16x8*)&stage[ldst]        = g0;
        *(bf16x8*)&stage[ldst + 512]  = g1;
        *(bf16x8*)&stage[ldst + 1024] = g2;
        *(bf16x8*)&stage[ldst + 1536] = g3;
    }
    __syncthreads();

    for (int ks = 0; ks < 8; ++ks) {
        int cur = (ks & 1) * 8192;
        bf16x8 g0, g1, g2, g3;
        if (ks < 7) {
            const bf16* gs = gsrc + (size_t)(ks + 1) * 4096;
            g0 = *(const bf16x8*)(gs);
            g1 = *(const bf16x8*)(gs + 512);
            g2 = *(const bf16x8*)(gs + 1024);
            g3 = *(const bf16x8*)(gs + 1536);
        }
        bf16x8 a = *(const bf16x8*)(Ab + (size_t)ks * 512);
        int foff = cur + lane * 8;
#pragma unroll
        for (int dt = 0; dt < 8; ++dt) {
            bf16x8 bq = *(bf16x8*)&stage[foff + dt * 512];
            bf16x8 bm = *(bf16x8*)&stage[foff + 4096 + dt * 512];
            accA[dt] = MFMA16(a, bq, accA[dt]);
            accB[dt] = MFMA16(a, bm, accB[dt]);
        }
        if (ks < 7) {
            int nb = cur ^ 8192;
            *(bf16x8*)&stage[nb + ldst]        = g0;
            *(bf16x8*)&stage[nb + ldst + 512]  = g1;
            *(bf16x8*)&stage[nb + ldst + 1024] = g2;
            *(bf16x8*)&stage[nb + ldst + 1536] = g3;
        }
        __syncthreads();
    }

    f32x4 rs = (f32x4){0.f, 0.f, 0.f, 0.f};
#pragma unroll
    for (int s = 0; s < 4; ++s)
        rs += *(const f32x4*)(Rpart + ((size_t)(b * 4 + s)) * LC + c0 + wid * 16 + lg * 4);
    f32x4 rv;
#pragma unroll
    for (int j = 0; j < 4; ++j) rv[j] = 1.0f / fmaxf(rs[j], 1e-30f);

#pragma unroll
    for (int dt = 0; dt < 8; ++dt) {
        f32x4 a4 = accA[dt] * rv;
        f32x4 b4 = accB[dt] * rv;
        bf16x4 pa = { (bf16)a4[0], (bf16)a4[1], (bf16)a4[2], (bf16)a4[3] };
        bf16x4 pb = { (bf16)b4[0], (bf16)b4[1], (bf16)b4[2], (bf16)b4[3] };
        *(bf16x4*)&ldsA[dt * 16 + lr][wid * 16 + lg * 4] = pa;
        *(bf16x4*)&ldsB[dt * 16 + lr][wid * 16 + lg * 4] = pb;
    }
    __syncthreads();

    float* obase = out + ((size_t)b * 512) * LC;
#pragma unroll
    for (int pass = 0; pass < 8; ++pass) {
        int d = pass * 16 + (t >> 4);
        int cq = (t & 15) * 4;
        int cglob = c0 + cq;
        int cb32 = cglob >> 5, ci = cglob & 31;
        bf16x4 av = *(bf16x4*)&ldsA[d][cq];
        bf16x4 bv = *(bf16x4*)&ldsB[d][cq];
        bf16x4 cb4 = *(const bf16x4*)(CbTp + ((size_t)(b * 64 + cb32) * 128 + d) * 32 + ci);
        float4 c4 = {(float)cb4[0], (float)cb4[1], (float)cb4[2], (float)cb4[3]};
        float4 a4 = {(float)av[0], (float)av[1], (float)av[2], (float)av[3]};
        float4 b4 = {(float)bv[0], (float)bv[1], (float)bv[2], (float)bv[3]};
        *(float4*)(obase + (size_t)(128 + d) * LC + c0 + cq) = a4;
        *(float4*)(obase + (size_t)(256 + d) * LC + c0 + cq) =
            (float4){c4.x * a4.x, c4.y * a4.y, c4.z * a4.z, c4.w * a4.w};
        *(float4*)(obase + (size_t)(384 + d) * LC + c0 + cq) =
            (float4){c4.x * b4.x, c4.y * b4.y, c4.z * b4.z, c4.w * b4.w};
    }
}

// ---------------------------------------------------------------------------
extern "C" void kernel_launch(void* const* d_in, const int* in_sizes, int n_in,
                              void* d_out, int out_size, void* d_ws, size_t ws_size,
                              hipStream_t stream)
{
    const float* C     = (const float*)d_in[0];
    const float* Q     = (const float*)d_in[1];
    const float* Cmask = (const float*)d_in[2];
    const float* Qmask = (const float*)d_in[3];
    const float* w4C   = (const float*)d_in[4];
    const float* w4Q   = (const float*)d_in[5];
    const float* w4mlu = (const float*)d_in[6];
    const float* bias  = (const float*)d_in[7];
    float* out = (float*)d_out;

    char* ws = (char*)d_ws;
    size_t off = 0;
    auto alloc = [&](size_t bytes) -> char* {
        char* p = ws + off;
        off += (bytes + 255) & ~(size_t)255;
        return p;
    };
    bf16* Cwp   = (bf16*)alloc((size_t)B_ * LC * DD * 2);
    bf16* CbTp  = (bf16*)alloc((size_t)B_ * LC * DD * 2);
    bf16* Qbp   = (bf16*)alloc((size_t)B_ * LQ * DD * 2);
    bf16* QbTp  = (bf16*)alloc((size_t)B_ * LQ * DD * 2);
    bf16* Pp    = (bf16*)alloc((size_t)B_ * LC * LQ * 2);
    bf16* PTp   = (bf16*)alloc((size_t)B_ * LC * LQ * 2);
    bf16* MTp   = (bf16*)alloc((size_t)8 * B_ * DD * LQ * 2);
    bf16* MTpn  = (bf16*)alloc((size_t)B_ * DD * LQ * 2);
    float* sub0 = (float*)alloc((size_t)B_ * LC * 4);
    float* sub1 = (float*)alloc((size_t)B_ * LQ * 4);
    float* Rpart = (float*)alloc((size_t)B_ * 4 * LC * 4);
    float* Lpart = (float*)alloc((size_t)B_ * 64 * LQ * 4);
    (void)ws_size; (void)in_sizes; (void)n_in; (void)out_size;

    hipLaunchKernelGGL(k_prep_c, dim3(B_ * 32), dim3(256), 0, stream,
                       C, w4C, w4mlu, Cwp, CbTp, sub0, out);
    hipLaunchKernelGGL(k_prep_q, dim3(B_ * 4), dim3(256), 0, stream,
                       Q, w4Q, Qbp, QbTp, sub1);
    hipLaunchKernelGGL(k_s, dim3(16, 4, B_), dim3(256), 0, stream,
                       Cwp, Qbp, sub0, sub1, Qmask, Cmask, bias, Pp, PTp, Rpart, Lpart);
    hipLaunchKernelGGL(k_m, dim3(4, 8, B_), dim3(256), 0, stream, CbTp, PTp, MTp);
    hipLaunchKernelGGL(k_m2, dim3(4, B_), dim3(256), 0, stream, MTp, Lpart, MTpn);
    hipLaunchKernelGGL(k_out, dim3(32, B_), dim3(256), 0, stream,
                       Pp, QbTp, MTpn, CbTp, Rpart, out);
}

// Round 9
// 221.559 us; speedup vs baseline: 1.8879x; 1.0531x over previous
//
#include <hip/hip_runtime.h>

#define B_ 64
#define LC 2048
#define LQ 256
#define DD 128

typedef __bf16 bf16;
typedef __bf16 bf16x8 __attribute__((ext_vector_type(8)));
typedef __bf16 bf16x4 __attribute__((ext_vector_type(4)));
typedef float f32x4 __attribute__((ext_vector_type(4)));

#define MFMA16(a, b, c) __builtin_amdgcn_mfma_f32_16x16x32_bf16((a), (b), (c), 0, 0, 0)

// Panel layouts (bf16, chunk = 512 elems = 1KB), within-chunk LANE-LINEAR:
// fragment for MFMA-lane l sits at elems [l*8 .. l*8+7].
//  Cwp  [b][cb  (LC/16)][ks 4 ][512]  frag(lr,lg): c=cb*16+lr, d=ks*32+lg*8+i
//  Qbp  [b][qb  (LQ/16)][ks 4 ][512]  frag(lr,lg): q=qb*16+lr, d=ks*32+lg*8+i
//  QbTp [b][ks  (LQ/32)][dt 8 ][512]  frag(lr,lg): d=dt*16+lr, q=ks*32+lg*8+i
//  CbTp [b][cb32(LC/32)][d 128][32 ]  elem (c=cb32*32+ci, d)
//  Pp   [b][cb  (LC/16)][ks 8 ][512]  frag(lr,lg): c=cb*16+lr, q=ks*32+lg*8+i
//  PTp  [b][qb  (LQ/16)][cks64][512]  frag(lr,lg): q=qb*16+lr, c=cks*32+lg*8+i
//  MTpn [b][ks 8][dt 8][512]          frag(lr,lg): d=dt*16+lr, q=ks*32+lg*8+i (Linv folded)

// ---------------------------------------------------------------------------
// K1 (merged preps): blocks 0..2047 = C path; 2048..2303 = Q path.
// ---------------------------------------------------------------------------
__global__ __launch_bounds__(256) void k_prep(const float* __restrict__ C,
    const float* __restrict__ Q, const float* __restrict__ w4C,
    const float* __restrict__ w4Q, const float* __restrict__ w4mlu,
    bf16* __restrict__ Cwp, bf16* __restrict__ CbTp,
    bf16* __restrict__ Qbp, bf16* __restrict__ QbTp,
    float* __restrict__ sub0, float* __restrict__ sub1, float* __restrict__ out)
{
    __shared__ float lds[64][DD + 4];
    int t = threadIdx.x;
    if (blockIdx.x < 2048) {
        int b = blockIdx.x >> 5, ct = blockIdx.x & 31;
        int c0 = ct * 64;
        int r = t >> 2, cb = (t & 3) * 32;
        size_t rowoff = ((size_t)(b * LC + c0 + r)) * DD + cb;
        const float4* src = (const float4*)(C + rowoff);
        float s0 = 0.f;
#pragma unroll
        for (int i = 0; i < 8; ++i) {
            float4 v = src[i];
            int d = cb + i * 4;
            lds[r][d] = v.x; lds[r][d + 1] = v.y; lds[r][d + 2] = v.z; lds[r][d + 3] = v.w;
            s0 += v.x * w4C[d] + v.y * w4C[d + 1] + v.z * w4C[d + 2] + v.w * w4C[d + 3];
        }
        s0 += __shfl_xor(s0, 1);
        s0 += __shfl_xor(s0, 2);
        if ((t & 3) == 0) sub0[b * LC + c0 + r] = s0;
        __syncthreads();

        // Cwp panels: 16 chunks (cb_l 0..3, ks 0..3), lane-linear
#pragma unroll
        for (int p = 0; p < 4; ++p) {
            int idx = p * 256 + t;
            int chunk = idx >> 6, w = idx & 63;
            int cb_l = chunk >> 2, ks = chunk & 3;
            int lr = w & 15, lg = w >> 4;
            int c_l = cb_l * 16 + lr, d0 = ks * 32 + lg * 8;
            bf16x8 v;
#pragma unroll
            for (int j = 0; j < 8; ++j) v[j] = (bf16)(lds[c_l][d0 + j] * w4mlu[d0 + j]);
            size_t off = ((size_t)((b * 128 + ct * 4 + cb_l) * 4 + ks)) * 512 + w * 8;
            *(bf16x8*)(Cwp + off) = v;
        }
        // CbTp panels
#pragma unroll
        for (int p = 0; p < 4; ++p) {
            int idx = p * 256 + t;
            int cb32 = idx >> 9, rem = idx & 511;
            int d = rem >> 2, lg = rem & 3;
            int cl0 = cb32 * 32 + lg * 8;
            bf16x8 v;
#pragma unroll
            for (int j = 0; j < 8; ++j) v[j] = (bf16)lds[cl0 + j][d];
            size_t off = ((size_t)((b * 64 + ct * 2 + cb32) * 128 + d)) * 32 + lg * 8;
            *(bf16x8*)(CbTp + off) = v;
        }
        // out block 0: exact fp32 C^T, 256-B runs
#pragma unroll
        for (int p = 0; p < 8; ++p) {
            int d = p * 16 + (t >> 4);
            int cl = (t & 15) * 4;
            float4 v = {lds[cl][d], lds[cl + 1][d], lds[cl + 2][d], lds[cl + 3][d]};
            *(float4*)(out + ((size_t)(b * 512 + d)) * LC + c0 + cl) = v;
        }
    } else {
        int idx0 = blockIdx.x - 2048;
        int b = idx0 >> 2, qt = idx0 & 3;
        int q0 = qt * 64;
        bf16* ldsb = (bf16*)lds;   // reuse as bf16 [64][132]
        int r = t >> 2, cb = (t & 3) * 32;
        size_t rowoff = ((size_t)(b * LQ + q0 + r)) * DD + cb;
        const float4* src = (const float4*)(Q + rowoff);
        float s1 = 0.f;
#pragma unroll
        for (int i = 0; i < 8; ++i) {
            float4 v = src[i];
            int d = cb + i * 4;
            ldsb[r * 132 + d] = (bf16)v.x; ldsb[r * 132 + d + 1] = (bf16)v.y;
            ldsb[r * 132 + d + 2] = (bf16)v.z; ldsb[r * 132 + d + 3] = (bf16)v.w;
            s1 += v.x * w4Q[d] + v.y * w4Q[d + 1] + v.z * w4Q[d + 2] + v.w * w4Q[d + 3];
        }
        s1 += __shfl_xor(s1, 1);
        s1 += __shfl_xor(s1, 2);
        if ((t & 3) == 0) sub1[b * LQ + q0 + r] = s1;
        __syncthreads();

        // Qbp: lane-linear chunks
#pragma unroll
        for (int p = 0; p < 4; ++p) {
            int idx = p * 256 + t;
            int chunk = idx >> 6, w = idx & 63;
            int qb_l = chunk >> 2, ks = chunk & 3;
            int lr = w & 15, lg = w >> 4;
            bf16x8 v = *(bf16x8*)&ldsb[(qb_l * 16 + lr) * 132 + ks * 32 + lg * 8];
            size_t off = ((size_t)((b * 16 + qt * 4 + qb_l) * 4 + ks)) * 512 + w * 8;
            *(bf16x8*)(Qbp + off) = v;
        }
        // QbTp: lane-linear chunks, q-gather
#pragma unroll
        for (int p = 0; p < 4; ++p) {
            int idx = p * 256 + t;
            int chunk = idx >> 6, w = idx & 63;
            int ks_l = chunk >> 3, dt = chunk & 7;
            int lr = w & 15, lg = w >> 4;
            int d = dt * 16 + lr, ql = ks_l * 32 + lg * 8;
            bf16x8 v;
#pragma unroll
            for (int j = 0; j < 8; ++j) v[j] = ldsb[(ql + j) * 132 + d];
            size_t off = ((size_t)((b * 8 + qt * 2 + ks_l) * 8 + dt)) * 512 + w * 8;
            *(bf16x8*)(QbTp + off) = v;
        }
    }
}

// ---------------------------------------------------------------------------
// K2: S = Cw@Qb^T + subs + bias; P = Qm*exp(S-8); panels Pp, PTp(=P*Cm);
//     Rpart rowsum partials, Lpart masked colsum partials.
// grid (16 ct, 4 qt, B), 256 thr (4 waves); block 128c x 64q
// ---------------------------------------------------------------------------
__global__ __launch_bounds__(256) void k_s(const bf16* __restrict__ Cwp,
    const bf16* __restrict__ Qbp, const float* __restrict__ sub0,
    const float* __restrict__ sub1, const float* __restrict__ Qmask,
    const float* __restrict__ Cmask, const float* __restrict__ bias,
    bf16* __restrict__ Pp, bf16* __restrict__ PTp,
    float* __restrict__ Rpart, float* __restrict__ Lpart)
{
    __shared__ bf16 ldsP[128][80];    // [c_local][q_local]
    __shared__ bf16 ldsPT[64][136];   // [q_local][c_local]
    int b = blockIdx.z, qt = blockIdx.y, ctile = blockIdx.x;
    int q0 = qt * 64;
    int t = threadIdx.x, wid = t >> 6, lane = t & 63;
    int lr = lane & 15, lg = lane >> 4;
    int rowbase = ctile * 128 + wid * 32;

    f32x4 acc[2][4];
#pragma unroll
    for (int rt = 0; rt < 2; ++rt)
#pragma unroll
        for (int ct = 0; ct < 4; ++ct) acc[rt][ct] = (f32x4){0.f, 0.f, 0.f, 0.f};

    const bf16* Ab = Cwp + ((size_t)((b * 128 + ctile * 8 + wid * 2) * 4)) * 512 + lane * 8;
    const bf16* Bb = Qbp + ((size_t)((b * 16 + qt * 4) * 4)) * 512 + lane * 8;
#pragma unroll
    for (int ks = 0; ks < 4; ++ks) {
        bf16x8 a0 = *(const bf16x8*)(Ab + (size_t)ks * 512);
        bf16x8 a1 = *(const bf16x8*)(Ab + (size_t)(4 + ks) * 512);
#pragma unroll
        for (int ct = 0; ct < 4; ++ct) {
            bf16x8 bb = *(const bf16x8*)(Bb + (size_t)(ct * 4 + ks) * 512);
            acc[0][ct] = MFMA16(a0, bb, acc[0][ct]);
            acc[1][ct] = MFMA16(a1, bb, acc[1][ct]);
        }
    }

    float biasv = bias[0];
    float sub0v[2][4], cmv[2][4];
#pragma unroll
    for (int rt = 0; rt < 2; ++rt)
#pragma unroll
        for (int j = 0; j < 4; ++j) {
            int idx = b * LC + rowbase + rt * 16 + lg * 4 + j;
            sub0v[rt][j] = sub0[idx];
            cmv[rt][j] = Cmask[idx];
        }

    float rsum[2][4] = {};
#pragma unroll
    for (int ct = 0; ct < 4; ++ct) {
        int q = q0 + ct * 16 + lr;
        float s1v = sub1[b * LQ + q] + biasv;
        float qm = Qmask[b * LQ + q];
        float colsum = 0.f;
#pragma unroll
        for (int rt = 0; rt < 2; ++rt) {
            bf16x4 ptv;
#pragma unroll
            for (int j = 0; j < 4; ++j) {
                float S = acc[rt][ct][j] + sub0v[rt][j] + s1v;
                float Pv = __expf(S - 8.0f) * qm;
                rsum[rt][j] += Pv;
                float pm = Pv * cmv[rt][j];
                colsum += pm;
                ptv[j] = (bf16)pm;
                ldsP[wid * 32 + rt * 16 + lg * 4 + j][ct * 16 + lr] = (bf16)Pv;
            }
            *(bf16x4*)&ldsPT[ct * 16 + lr][wid * 32 + rt * 16 + lg * 4] = ptv;
        }
        colsum += __shfl_xor(colsum, 16);
        colsum += __shfl_xor(colsum, 32);
        if (lg == 0)
            Lpart[((size_t)(b * 64 + ctile * 4 + wid)) * LQ + q] = colsum;
    }
#pragma unroll
    for (int rt = 0; rt < 2; ++rt)
#pragma unroll
        for (int j = 0; j < 4; ++j) {
            float s = rsum[rt][j];
            s += __shfl_xor(s, 1);
            s += __shfl_xor(s, 2);
            s += __shfl_xor(s, 4);
            s += __shfl_xor(s, 8);
            if (lr == 0)
                Rpart[((size_t)(b * 4 + qt)) * LC + rowbase + rt * 16 + lg * 4 + j] = s;
        }
    __syncthreads();

    // Pp panels: 16 chunks (cb_l 0..7, ks_l 0..1), lane-linear
#pragma unroll
    for (int p = 0; p < 4; ++p) {
        int idx = p * 256 + t;
        int chunk = idx >> 6, w = idx & 63;
        int cb_l = chunk >> 1, ks_l = chunk & 1;
        int plr = w & 15, plg = w >> 4;
        bf16x8 v = *(bf16x8*)&ldsP[cb_l * 16 + plr][ks_l * 32 + plg * 8];
        size_t off = ((size_t)((b * 128 + ctile * 8 + cb_l) * 8 + qt * 2 + ks_l)) * 512 + w * 8;
        *(bf16x8*)(Pp + off) = v;
    }
    // PTp panels: 16 chunks (qb_l 0..3, cks_l 0..3), lane-linear
#pragma unroll
    for (int p = 0; p < 4; ++p) {
        int idx = p * 256 + t;
        int chunk = idx >> 6, w = idx & 63;
        int qb_l = chunk >> 2, cks_l = chunk & 3;
        int plr = w & 15, plg = w >> 4;
        bf16x8 v = *(bf16x8*)&ldsPT[qb_l * 16 + plr][cks_l * 32 + plg * 8];
        size_t off = ((size_t)((b * 16 + qt * 4 + qb_l) * 64 + ctile * 4 + cks_l)) * 512 + w * 8;
        *(bf16x8*)(PTp + off) = v;
    }
}

// ---------------------------------------------------------------------------
// K3: 4-way K-split GEMM: MTp slice = sum over 512 c of CbT[d][c]*PT[q][c]
// grid (4 qt, 4 ksl, B), 256 thr; 16 K-steps; staged LDS dbuf, lane-linear.
// ---------------------------------------------------------------------------
__global__ __launch_bounds__(256) void k_m(const bf16* __restrict__ CbTp,
    const bf16* __restrict__ PTp, bf16* __restrict__ MTp)
{
    __shared__ bf16 stage[2 * 2048];   // 8 KB
    int b = blockIdx.z, ksl = blockIdx.y, qt = blockIdx.x;
    int t = threadIdx.x, wid = t >> 6, lane = t & 63;
    int lr = lane & 15, lg = lane >> 4;
    int dbase = wid * 32;

    f32x4 acc[2][4];
#pragma unroll
    for (int rt = 0; rt < 2; ++rt)
#pragma unroll
        for (int ct = 0; ct < 4; ++ct) acc[rt][ct] = (f32x4){0.f, 0.f, 0.f, 0.f};

    // FIXED (round-8 bug): the whole (b,cb32,d) index must be scaled by 32.
    const bf16* Ab = CbTp + ((size_t)(b * 64 + ksl * 16) * 128 + dbase + lr) * 32 + lg * 8;
    const bf16* Bsrc = PTp + ((size_t)((b * 16 + qt * 4 + wid) * 64 + ksl * 16)) * 512 + lane * 8;
    int ldst = wid * 512 + lane * 8;

    *(bf16x8*)&stage[ldst] = *(const bf16x8*)(Bsrc);
    __syncthreads();

    for (int ks = 0; ks < 16; ++ks) {
        int cur = (ks & 1) * 2048;
        bf16x8 g;
        if (ks < 15) g = *(const bf16x8*)(Bsrc + (size_t)(ks + 1) * 512);
        bf16x8 a0 = *(const bf16x8*)(Ab + (size_t)ks * 4096);
        bf16x8 a1 = *(const bf16x8*)(Ab + (size_t)ks * 4096 + 512);
#pragma unroll
        for (int ct = 0; ct < 4; ++ct) {
            bf16x8 bb = *(bf16x8*)&stage[cur + ct * 512 + lane * 8];
            acc[0][ct] = MFMA16(a0, bb, acc[0][ct]);
            acc[1][ct] = MFMA16(a1, bb, acc[1][ct]);
        }
        if (ks < 15) *(bf16x8*)&stage[(cur ^ 2048) + ldst] = g;
        __syncthreads();
    }

    size_t base = ((((size_t)ksl * B_ + b) * 4 + qt) * 4 + wid) * 2048;
#pragma unroll
    for (int rt = 0; rt < 2; ++rt)
#pragma unroll
        for (int ct = 0; ct < 4; ++ct)
#pragma unroll
            for (int j = 0; j < 4; ++j)
                MTp[base + (size_t)(rt * 16 + ct * 4 + j) * 64 + lane] = (bf16)acc[rt][ct][j];
}

// ---------------------------------------------------------------------------
// K4: reduce 4 K-slices + fold Linv -> MTpn (lane-linear chunks)
// grid (4, B), 256 thr
// ---------------------------------------------------------------------------
__global__ __launch_bounds__(256) void k_m2(const bf16* __restrict__ MTp,
    const float* __restrict__ Lpart, bf16* __restrict__ MTpn)
{
    __shared__ float ldsLinv[256];
    int b = blockIdx.y, ih = blockIdx.x;
    int t = threadIdx.x;
    {
        float s = 0.f;
#pragma unroll
        for (int sl = 0; sl < 64; ++sl) s += Lpart[((size_t)(b * 64 + sl)) * LQ + t];
        ldsLinv[t] = 1.0f / fmaxf(s, 1e-30f);
    }
    __syncthreads();
#pragma unroll
    for (int i = 0; i < 4; ++i) {
        int slot = (ih * 4 + i) * 256 + t;    // 0..4095
        int d = slot >> 5, qo = slot & 31;
        int q0 = qo * 8;
        int qt = q0 >> 6, ct = (q0 >> 4) & 3, lr0 = q0 & 15;
        int wid = d >> 5, rt = (d >> 4) & 1, lgd = (d >> 2) & 3, j = d & 3;
        size_t roff = ((size_t)(b * 4 + qt)) * 8192 + wid * 2048
                      + (rt * 16 + ct * 4 + j) * 64 + lgd * 16 + lr0;
        float a8[8] = {0.f, 0.f, 0.f, 0.f, 0.f, 0.f, 0.f, 0.f};
#pragma unroll
        for (int sl = 0; sl < 4; ++sl) {
            bf16x8 x = *(const bf16x8*)(MTp + (size_t)sl * B_ * 32768 + roff);
#pragma unroll
            for (int k = 0; k < 8; ++k) a8[k] += (float)x[k];
        }
        bf16x8 o;
#pragma unroll
        for (int k = 0; k < 8; ++k) o[k] = (bf16)(a8[k] * ldsLinv[q0 + k]);
        size_t woff = ((size_t)((b * 8 + (qo >> 2)) * 8 + (d >> 4))) * 512
                      + ((qo & 3) * 16 + (d & 15)) * 8;
        *(bf16x8*)(MTpn + woff) = o;
    }
}

// ---------------------------------------------------------------------------
// K5: A = Rinv*(P@Qb), Bt = Rinv*(P@M).
//   2-phase reg-staged LDS dbuf of Q/M panels; lane-linear conflict-free reads.
//   Rinv hoisted above the K-loop. Epilogue unions transpose buffers; C from CbTp.
// grid (32 ctile, B), 256 thr (4 waves)
// ---------------------------------------------------------------------------
__global__ __launch_bounds__(256) void k_out(const bf16* __restrict__ Pp,
    const bf16* __restrict__ QbTp, const bf16* __restrict__ MTpn,
    const bf16* __restrict__ CbTp, const float* __restrict__ Rpart,
    float* __restrict__ out)
{
    __shared__ f32x4 smem4[2304];                       // 36864 B
    bf16* stage = (bf16*)smem4;                         // stage[2][8192] (32 KB)
    bf16 (*ldsA)[72] = (bf16(*)[72])smem4;              // epilogue-only (union)
    bf16 (*ldsB)[72] = (bf16(*)[72])((char*)smem4 + 18432);

    int b = blockIdx.y, ctile = blockIdx.x;
    int t = threadIdx.x, wid = t >> 6, lane = t & 63;
    int lr = lane & 15, lg = lane >> 4;
    int c0 = ctile * 64;

    const bf16* gsrc = (wid < 2 ? QbTp : MTpn) + (size_t)b * 32768
                       + (size_t)(wid & 1) * 2048 + lane * 8;
    int ldst = wid * 2048 + lane * 8;

    f32x4 rs = (f32x4){0.f, 0.f, 0.f, 0.f};
#pragma unroll
    for (int s = 0; s < 4; ++s)
        rs += *(const f32x4*)(Rpart + ((size_t)(b * 4 + s)) * LC + c0 + wid * 16 + lg * 4);
    f32x4 rv;
#pragma unroll
    for (int j = 0; j < 4; ++j) rv[j] = 1.0f / fmaxf(rs[j], 1e-30f);

    f32x4 accA[8], accB[8];
#pragma unroll
    for (int dt = 0; dt < 8; ++dt) {
        accA[dt] = (f32x4){0.f, 0.f, 0.f, 0.f};
        accB[dt] = (f32x4){0.f, 0.f, 0.f, 0.f};
    }
    const bf16* Ab = Pp + ((size_t)((b * 128 + ctile * 4 + wid) * 8)) * 512 + lane * 8;

    {
        bf16x8 g0 = *(const bf16x8*)(gsrc);
        bf16x8 g1 = *(const bf16x8*)(gsrc + 512);
        bf16x8 g2 = *(const bf16x8*)(gsrc + 1024);
        bf16x8 g3 = *(const bf16x8*)(gsrc + 1536);
        *(bf16x8*)&stage[ldst]        = g0;
        *(bf16x8*)&stage[ldst + 512]  = g1;
        *(bf16x8*)&stage[ldst + 1024] = g2;
        *(bf16x8*)&stage[ldst + 1536] = g3;
    }
    __syncthreads();

    for (int ks = 0; ks < 8; ++ks) {
        int cur = (ks & 1) * 8192;
        bf16x8 g0, g1, g2, g3;
        if (ks < 7) {
            const bf16* gs = gsrc + (size_t)(ks + 1) * 4096;
            g0 = *(const bf16x8*)(gs);
            g1 = *(const bf16x8*)(gs + 512);
            g2 = *(const bf16x8*)(gs + 1024);
            g3 = *(const bf16x8*)(gs + 1536);
        }
        bf16x8 a = *(const bf16x8*)(Ab + (size_t)ks * 512);
        int foff = cur + lane * 8;
#pragma unroll
        for (int dt = 0; dt < 8; ++dt) {
            bf16x8 bq = *(bf16x8*)&stage[foff + dt * 512];
            bf16x8 bm = *(bf16x8*)&stage[foff + 4096 + dt * 512];
            accA[dt] = MFMA16(a, bq, accA[dt]);
            accB[dt] = MFMA16(a, bm, accB[dt]);
        }
        if (ks < 7) {
            int nb = cur ^ 8192;
            *(bf16x8*)&stage[nb + ldst]        = g0;
            *(bf16x8*)&stage[nb + ldst + 512]  = g1;
            *(bf16x8*)&stage[nb + ldst + 1024] = g2;
            *(bf16x8*)&stage[nb + ldst + 1536] = g3;
        }
        __syncthreads();
    }

#pragma unroll
    for (int dt = 0; dt < 8; ++dt) {
        f32x4 a4 = accA[dt] * rv;
        f32x4 b4 = accB[dt] * rv;
        bf16x4 pa = { (bf16)a4[0], (bf16)a4[1], (bf16)a4[2], (bf16)a4[3] };
        bf16x4 pb = { (bf16)b4[0], (bf16)b4[1], (bf16)b4[2], (bf16)b4[3] };
        *(bf16x4*)&ldsA[dt * 16 + lr][wid * 16 + lg * 4] = pa;
        *(bf16x4*)&ldsB[dt * 16 + lr][wid * 16 + lg * 4] = pb;
    }
    __syncthreads();

    float* obase = out + ((size_t)b * 512) * LC;
#pragma unroll
    for (int pass = 0; pass < 8; ++pass) {
        int d = pass * 16 + (t >> 4);
        int cq = (t & 15) * 4;
        int cglob = c0 + cq;
        int cb32 = cglob >> 5, ci = cglob & 31;
        bf16x4 av = *(bf16x4*)&ldsA[d][cq];
        bf16x4 bv = *(bf16x4*)&ldsB[d][cq];
        bf16x4 cb4 = *(const bf16x4*)(CbTp + ((size_t)(b * 64 + cb32) * 128 + d) * 32 + ci);
        float4 c4 = {(float)cb4[0], (float)cb4[1], (float)cb4[2], (float)cb4[3]};
        float4 a4 = {(float)av[0], (float)av[1], (float)av[2], (float)av[3]};
        float4 b4 = {(float)bv[0], (float)bv[1], (float)bv[2], (float)bv[3]};
        *(float4*)(obase + (size_t)(128 + d) * LC + c0 + cq) = a4;
        *(float4*)(obase + (size_t)(256 + d) * LC + c0 + cq) =
            (float4){c4.x * a4.x, c4.y * a4.y, c4.z * a4.z, c4.w * a4.w};
        *(float4*)(obase + (size_t)(384 + d) * LC + c0 + cq) =
            (float4){c4.x * b4.x, c4.y * b4.y, c4.z * b4.z, c4.w * b4.w};
    }
}

// ---------------------------------------------------------------------------
extern "C" void kernel_launch(void* const* d_in, const int* in_sizes, int n_in,
                              void* d_out, int out_size, void* d_ws, size_t ws_size,
                              hipStream_t stream)
{
    const float* C     = (const float*)d_in[0];
    const float* Q     = (const float*)d_in[1];
    const float* Cmask = (const float*)d_in[2];
    const float* Qmask = (const float*)d_in[3];
    const float* w4C   = (const float*)d_in[4];
    const float* w4Q   = (const float*)d_in[5];
    const float* w4mlu = (const float*)d_in[6];
    const float* bias  = (const float*)d_in[7];
    float* out = (float*)d_out;

    char* ws = (char*)d_ws;
    size_t off = 0;
    auto alloc = [&](size_t bytes) -> char* {
        char* p = ws + off;
        off += (bytes + 255) & ~(size_t)255;
        return p;
    };
    bf16* Cwp   = (bf16*)alloc((size_t)B_ * LC * DD * 2);
    bf16* CbTp  = (bf16*)alloc((size_t)B_ * LC * DD * 2);
    bf16* Qbp   = (bf16*)alloc((size_t)B_ * LQ * DD * 2);
    bf16* QbTp  = (bf16*)alloc((size_t)B_ * LQ * DD * 2);
    bf16* Pp    = (bf16*)alloc((size_t)B_ * LC * LQ * 2);
    bf16* PTp   = (bf16*)alloc((size_t)B_ * LC * LQ * 2);
    bf16* MTp   = (bf16*)alloc((size_t)4 * B_ * DD * LQ * 2);
    bf16* MTpn  = (bf16*)alloc((size_t)B_ * DD * LQ * 2);
    float* sub0 = (float*)alloc((size_t)B_ * LC * 4);
    float* sub1 = (float*)alloc((size_t)B_ * LQ * 4);
    float* Rpart = (float*)alloc((size_t)B_ * 4 * LC * 4);
    float* Lpart = (float*)alloc((size_t)B_ * 64 * LQ * 4);
    (void)ws_size; (void)in_sizes; (void)n_in; (void)out_size;

    hipLaunchKernelGGL(k_prep, dim3(2304), dim3(256), 0, stream,
                       C, Q, w4C, w4Q, w4mlu, Cwp, CbTp, Qbp, QbTp, sub0, sub1, out);
    hipLaunchKernelGGL(k_s, dim3(16, 4, B_), dim3(256), 0, stream,
                       Cwp, Qbp, sub0, sub1, Qmask, Cmask, bias, Pp, PTp, Rpart, Lpart);
    hipLaunchKernelGGL(k_m, dim3(4, 4, B_), dim3(256), 0, stream, CbTp, PTp, MTp);
    hipLaunchKernelGGL(k_m2, dim3(4, B_), dim3(256), 0, stream, MTp, Lpart, MTpn);
    hipLaunchKernelGGL(k_out, dim3(32, B_), dim3(256), 0, stream,
                       Pp, QbTp, MTpn, CbTp, Rpart, out);
}

// Round 10
// 203.813 us; speedup vs baseline: 2.0522x; 1.0871x over previous
//
#include <hip/hip_runtime.h>

#define B_ 64
#define LC 2048
#define LQ 256
#define DD 128

typedef __bf16 bf16;
typedef __bf16 bf16x8 __attribute__((ext_vector_type(8)));
typedef __bf16 bf16x4 __attribute__((ext_vector_type(4)));
typedef float f32x4 __attribute__((ext_vector_type(4)));

#define MFMA16(a, b, c) __builtin_amdgcn_mfma_f32_16x16x32_bf16((a), (b), (c), 0, 0, 0)

// Panel layouts (bf16, chunk = 512 elems = 1KB), within-chunk LANE-LINEAR:
// fragment for MFMA-lane l sits at elems [l*8 .. l*8+7].
//  Cwp   [b][cb  (LC/16)][ks 4 ][512]  frag(lr,lg): c=cb*16+lr, d=ks*32+lg*8+i  (*w4mlu)
//  Qbp   [b][qb  (LQ/16)][ks 4 ][512]  frag(lr,lg): q=qb*16+lr, d=ks*32+lg*8+i
//  QbTp  [b][ks  (LQ/32)][dt 8 ][512]  frag(lr,lg): d=dt*16+lr, q=ks*32+lg*8+i
//  CbTmp [b][cb32(LC/32)][d 128][32 ]  elem (c=cb32*32+ci, d) = bf16(C*Cmask)^T
//  Pp    [b][cb  (LC/16)][ks 8 ][512]  frag(lr,lg): c=cb*16+lr, q=ks*32+lg*8+i (UNmasked)
//  MTpn  [b][ks 8][dt 8][512]          frag(lr,lg): d=dt*16+lr, q=ks*32+lg*8+i (Linv folded)
// Cmask folded into CbTmp (A-side of k_m); k_out reads exact fp32 C from out block 0.

// ---------------------------------------------------------------------------
// K1 (merged preps): blocks 0..2047 = C path; 2048..2303 = Q path.
// ---------------------------------------------------------------------------
__global__ __launch_bounds__(256) void k_prep(const float* __restrict__ C,
    const float* __restrict__ Q, const float* __restrict__ Cmask,
    const float* __restrict__ w4C, const float* __restrict__ w4Q,
    const float* __restrict__ w4mlu,
    bf16* __restrict__ Cwp, bf16* __restrict__ CbTmp,
    bf16* __restrict__ Qbp, bf16* __restrict__ QbTp,
    float* __restrict__ sub0, float* __restrict__ sub1, float* __restrict__ out)
{
    __shared__ float lds[64][DD + 4];
    __shared__ float ldsM[64];
    int t = threadIdx.x;
    if (blockIdx.x < 2048) {
        int b = blockIdx.x >> 5, ct = blockIdx.x & 31;
        int c0 = ct * 64;
        int r = t >> 2, cb = (t & 3) * 32;
        size_t rowoff = ((size_t)(b * LC + c0 + r)) * DD + cb;
        const float4* src = (const float4*)(C + rowoff);
        if ((t & 3) == 0) ldsM[r] = Cmask[b * LC + c0 + r];
        float s0 = 0.f;
#pragma unroll
        for (int i = 0; i < 8; ++i) {
            float4 v = src[i];
            int d = cb + i * 4;
            lds[r][d] = v.x; lds[r][d + 1] = v.y; lds[r][d + 2] = v.z; lds[r][d + 3] = v.w;
            s0 += v.x * w4C[d] + v.y * w4C[d + 1] + v.z * w4C[d + 2] + v.w * w4C[d + 3];
        }
        s0 += __shfl_xor(s0, 1);
        s0 += __shfl_xor(s0, 2);
        if ((t & 3) == 0) sub0[b * LC + c0 + r] = s0;
        __syncthreads();

        // Cwp panels: 16 chunks (cb_l 0..3, ks 0..3), lane-linear
#pragma unroll
        for (int p = 0; p < 4; ++p) {
            int idx = p * 256 + t;
            int chunk = idx >> 6, w = idx & 63;
            int cb_l = chunk >> 2, ks = chunk & 3;
            int lr = w & 15, lg = w >> 4;
            int c_l = cb_l * 16 + lr, d0 = ks * 32 + lg * 8;
            bf16x8 v;
#pragma unroll
            for (int j = 0; j < 8; ++j) v[j] = (bf16)(lds[c_l][d0 + j] * w4mlu[d0 + j]);
            size_t off = ((size_t)((b * 128 + ct * 4 + cb_l) * 4 + ks)) * 512 + w * 8;
            *(bf16x8*)(Cwp + off) = v;
        }
        // CbTmp panels (Cmask folded)
#pragma unroll
        for (int p = 0; p < 4; ++p) {
            int idx = p * 256 + t;
            int cb32 = idx >> 9, rem = idx & 511;
            int d = rem >> 2, lg = rem & 3;
            int cl0 = cb32 * 32 + lg * 8;
            bf16x8 v;
#pragma unroll
            for (int j = 0; j < 8; ++j) v[j] = (bf16)(lds[cl0 + j][d] * ldsM[cl0 + j]);
            size_t off = ((size_t)((b * 64 + ct * 2 + cb32) * 128 + d)) * 32 + lg * 8;
            *(bf16x8*)(CbTmp + off) = v;
        }
        // out block 0: exact fp32 C^T, 256-B runs (re-read by k_out via L3)
#pragma unroll
        for (int p = 0; p < 8; ++p) {
            int d = p * 16 + (t >> 4);
            int cl = (t & 15) * 4;
            float4 v = {lds[cl][d], lds[cl + 1][d], lds[cl + 2][d], lds[cl + 3][d]};
            *(float4*)(out + ((size_t)(b * 512 + d)) * LC + c0 + cl) = v;
        }
    } else {
        int idx0 = blockIdx.x - 2048;
        int b = idx0 >> 2, qt = idx0 & 3;
        int q0 = qt * 64;
        bf16* ldsb = (bf16*)lds;   // reuse as bf16 [64][132]
        int r = t >> 2, cb = (t & 3) * 32;
        size_t rowoff = ((size_t)(b * LQ + q0 + r)) * DD + cb;
        const float4* src = (const float4*)(Q + rowoff);
        float s1 = 0.f;
#pragma unroll
        for (int i = 0; i < 8; ++i) {
            float4 v = src[i];
            int d = cb + i * 4;
            ldsb[r * 132 + d] = (bf16)v.x; ldsb[r * 132 + d + 1] = (bf16)v.y;
            ldsb[r * 132 + d + 2] = (bf16)v.z; ldsb[r * 132 + d + 3] = (bf16)v.w;
            s1 += v.x * w4Q[d] + v.y * w4Q[d + 1] + v.z * w4Q[d + 2] + v.w * w4Q[d + 3];
        }
        s1 += __shfl_xor(s1, 1);
        s1 += __shfl_xor(s1, 2);
        if ((t & 3) == 0) sub1[b * LQ + q0 + r] = s1;
        __syncthreads();

        // Qbp: lane-linear chunks
#pragma unroll
        for (int p = 0; p < 4; ++p) {
            int idx = p * 256 + t;
            int chunk = idx >> 6, w = idx & 63;
            int qb_l = chunk >> 2, ks = chunk & 3;
            int lr = w & 15, lg = w >> 4;
            bf16x8 v = *(bf16x8*)&ldsb[(qb_l * 16 + lr) * 132 + ks * 32 + lg * 8];
            size_t off = ((size_t)((b * 16 + qt * 4 + qb_l) * 4 + ks)) * 512 + w * 8;
            *(bf16x8*)(Qbp + off) = v;
        }
        // QbTp: lane-linear chunks, q-gather
#pragma unroll
        for (int p = 0; p < 4; ++p) {
            int idx = p * 256 + t;
            int chunk = idx >> 6, w = idx & 63;
            int ks_l = chunk >> 3, dt = chunk & 7;
            int lr = w & 15, lg = w >> 4;
            int d = dt * 16 + lr, ql = ks_l * 32 + lg * 8;
            bf16x8 v;
#pragma unroll
            for (int j = 0; j < 8; ++j) v[j] = ldsb[(ql + j) * 132 + d];
            size_t off = ((size_t)((b * 8 + qt * 2 + ks_l) * 8 + dt)) * 512 + w * 8;
            *(bf16x8*)(QbTp + off) = v;
        }
    }
}

// ---------------------------------------------------------------------------
// K2: S = Cw@Qb^T + subs + bias; P = Qm*exp(S-8) -> Pp only;
//     Rpart rowsum partials, Lpart masked colsum partials (mask in-register).
// grid (16 ct, 4 qt, B), 256 thr (4 waves); block 128c x 64q; LDS 20.5 KB
// ---------------------------------------------------------------------------
__global__ __launch_bounds__(256) void k_s(const bf16* __restrict__ Cwp,
    const bf16* __restrict__ Qbp, const float* __restrict__ sub0,
    const float* __restrict__ sub1, const float* __restrict__ Qmask,
    const float* __restrict__ Cmask, const float* __restrict__ bias,
    bf16* __restrict__ Pp, float* __restrict__ Rpart, float* __restrict__ Lpart)
{
    __shared__ bf16 ldsP[128][80];    // [c_local][q_local]
    int b = blockIdx.z, qt = blockIdx.y, ctile = blockIdx.x;
    int q0 = qt * 64;
    int t = threadIdx.x, wid = t >> 6, lane = t & 63;
    int lr = lane & 15, lg = lane >> 4;
    int rowbase = ctile * 128 + wid * 32;

    f32x4 acc[2][4];
#pragma unroll
    for (int rt = 0; rt < 2; ++rt)
#pragma unroll
        for (int ct = 0; ct < 4; ++ct) acc[rt][ct] = (f32x4){0.f, 0.f, 0.f, 0.f};

    const bf16* Ab = Cwp + ((size_t)((b * 128 + ctile * 8 + wid * 2) * 4)) * 512 + lane * 8;
    const bf16* Bb = Qbp + ((size_t)((b * 16 + qt * 4) * 4)) * 512 + lane * 8;
#pragma unroll
    for (int ks = 0; ks < 4; ++ks) {
        bf16x8 a0 = *(const bf16x8*)(Ab + (size_t)ks * 512);
        bf16x8 a1 = *(const bf16x8*)(Ab + (size_t)(4 + ks) * 512);
#pragma unroll
        for (int ct = 0; ct < 4; ++ct) {
            bf16x8 bb = *(const bf16x8*)(Bb + (size_t)(ct * 4 + ks) * 512);
            acc[0][ct] = MFMA16(a0, bb, acc[0][ct]);
            acc[1][ct] = MFMA16(a1, bb, acc[1][ct]);
        }
    }

    float biasv = bias[0];
    float sub0v[2][4], cmv[2][4];
#pragma unroll
    for (int rt = 0; rt < 2; ++rt)
#pragma unroll
        for (int j = 0; j < 4; ++j) {
            int idx = b * LC + rowbase + rt * 16 + lg * 4 + j;
            sub0v[rt][j] = sub0[idx];
            cmv[rt][j] = Cmask[idx];
        }

    float rsum[2][4] = {};
#pragma unroll
    for (int ct = 0; ct < 4; ++ct) {
        int q = q0 + ct * 16 + lr;
        float s1v = sub1[b * LQ + q] + biasv;
        float qm = Qmask[b * LQ + q];
        float colsum = 0.f;
#pragma unroll
        for (int rt = 0; rt < 2; ++rt)
#pragma unroll
            for (int j = 0; j < 4; ++j) {
                float S = acc[rt][ct][j] + sub0v[rt][j] + s1v;
                float Pv = __expf(S - 8.0f) * qm;
                rsum[rt][j] += Pv;
                colsum += Pv * cmv[rt][j];
                ldsP[wid * 32 + rt * 16 + lg * 4 + j][ct * 16 + lr] = (bf16)Pv;
            }
        colsum += __shfl_xor(colsum, 16);
        colsum += __shfl_xor(colsum, 32);
        if (lg == 0)
            Lpart[((size_t)(b * 64 + ctile * 4 + wid)) * LQ + q] = colsum;
    }
#pragma unroll
    for (int rt = 0; rt < 2; ++rt)
#pragma unroll
        for (int j = 0; j < 4; ++j) {
            float s = rsum[rt][j];
            s += __shfl_xor(s, 1);
            s += __shfl_xor(s, 2);
            s += __shfl_xor(s, 4);
            s += __shfl_xor(s, 8);
            if (lr == 0)
                Rpart[((size_t)(b * 4 + qt)) * LC + rowbase + rt * 16 + lg * 4 + j] = s;
        }
    __syncthreads();

    // Pp panels: 16 chunks (cb_l 0..7, ks_l 0..1), lane-linear
#pragma unroll
    for (int p = 0; p < 4; ++p) {
        int idx = p * 256 + t;
        int chunk = idx >> 6, w = idx & 63;
        int cb_l = chunk >> 1, ks_l = chunk & 1;
        int plr = w & 15, plg = w >> 4;
        bf16x8 v = *(bf16x8*)&ldsP[cb_l * 16 + plr][ks_l * 32 + plg * 8];
        size_t off = ((size_t)((b * 128 + ctile * 8 + cb_l) * 8 + qt * 2 + ks_l)) * 512 + w * 8;
        *(bf16x8*)(Pp + off) = v;
    }
}

// ---------------------------------------------------------------------------
// K3: 4-way K-split GEMM: MTp slice = sum over 512 c of CbTm[d][c]*P[c][q]
//   (Cmask folded in CbTmp). B-operand built by transpose-on-ds_write from Pp:
//   stage [q 64][c 32, pad->40] per K-step; frag reads = b128, 8 lanes/quad.
// grid (4 qt, 4 ksl, B), 256 thr; 16 K-steps; double-buffered.
// ---------------------------------------------------------------------------
__global__ __launch_bounds__(256) void k_m(const bf16* __restrict__ CbTmp,
    const bf16* __restrict__ Pp, bf16* __restrict__ MTp)
{
    __shared__ bf16 stage[2][64 * 40];   // 2 x 5120 B
    int b = blockIdx.z, ksl = blockIdx.y, qt = blockIdx.x;
    int t = threadIdx.x, wid = t >> 6, lane = t & 63;
    int lr = lane & 15, lg = lane >> 4;
    int dbase = wid * 32;

    f32x4 acc[2][4];
#pragma unroll
    for (int rt = 0; rt < 2; ++rt)
#pragma unroll
        for (int ct = 0; ct < 4; ++ct) acc[rt][ct] = (f32x4){0.f, 0.f, 0.f, 0.f};

    const bf16* Ab = CbTmp + ((size_t)(b * 64 + ksl * 16) * 128 + dbase + lr) * 32 + lg * 8;
    // staging: chunk = wid: cb_off = wid&1 (c half), qh = wid>>1 (q half)
    int cb_off = wid & 1, qh = wid >> 1;
    const bf16* Bsrc = Pp + ((size_t)((b * 128 + ksl * 32 + cb_off) * 8) + qt * 2 + qh) * 512
                       + lane * 8;
    int c_local = cb_off * 16 + lr;
    int qrow = qh * 32 + lg * 8;

    {
        bf16x8 g = *(const bf16x8*)(Bsrc);
#pragma unroll
        for (int i = 0; i < 8; ++i) stage[0][(qrow + i) * 40 + c_local] = g[i];
    }
    __syncthreads();

    for (int ks = 0; ks < 16; ++ks) {
        int cur = ks & 1;
        bf16x8 g;
        if (ks < 15) g = *(const bf16x8*)(Bsrc + (size_t)(ks + 1) * 8192);
        bf16x8 a0 = *(const bf16x8*)(Ab + (size_t)ks * 4096);
        bf16x8 a1 = *(const bf16x8*)(Ab + (size_t)ks * 4096 + 512);
#pragma unroll
        for (int ct = 0; ct < 4; ++ct) {
            bf16x8 bb = *(bf16x8*)&stage[cur][(ct * 16 + lr) * 40 + lg * 8];
            acc[0][ct] = MFMA16(a0, bb, acc[0][ct]);
            acc[1][ct] = MFMA16(a1, bb, acc[1][ct]);
        }
        if (ks < 15) {
#pragma unroll
            for (int i = 0; i < 8; ++i) stage[cur ^ 1][(qrow + i) * 40 + c_local] = g[i];
        }
        __syncthreads();
    }

    size_t base = ((((size_t)ksl * B_ + b) * 4 + qt) * 4 + wid) * 2048;
#pragma unroll
    for (int rt = 0; rt < 2; ++rt)
#pragma unroll
        for (int ct = 0; ct < 4; ++ct)
#pragma unroll
            for (int j = 0; j < 4; ++j)
                MTp[base + (size_t)(rt * 16 + ct * 4 + j) * 64 + lane] = (bf16)acc[rt][ct][j];
}

// ---------------------------------------------------------------------------
// K4: reduce 4 K-slices + fold Linv -> MTpn (lane-linear chunks)
// grid (4, B), 256 thr
// ---------------------------------------------------------------------------
__global__ __launch_bounds__(256) void k_m2(const bf16* __restrict__ MTp,
    const float* __restrict__ Lpart, bf16* __restrict__ MTpn)
{
    __shared__ float ldsLinv[256];
    int b = blockIdx.y, ih = blockIdx.x;
    int t = threadIdx.x;
    {
        float s = 0.f;
#pragma unroll
        for (int sl = 0; sl < 64; ++sl) s += Lpart[((size_t)(b * 64 + sl)) * LQ + t];
        ldsLinv[t] = 1.0f / fmaxf(s, 1e-30f);
    }
    __syncthreads();
#pragma unroll
    for (int i = 0; i < 4; ++i) {
        int slot = (ih * 4 + i) * 256 + t;    // 0..4095
        int d = slot >> 5, qo = slot & 31;
        int q0 = qo * 8;
        int qt = q0 >> 6, ct = (q0 >> 4) & 3, lr0 = q0 & 15;
        int wid = d >> 5, rt = (d >> 4) & 1, lgd = (d >> 2) & 3, j = d & 3;
        size_t roff = ((size_t)(b * 4 + qt)) * 8192 + wid * 2048
                      + (rt * 16 + ct * 4 + j) * 64 + lgd * 16 + lr0;
        float a8[8] = {0.f, 0.f, 0.f, 0.f, 0.f, 0.f, 0.f, 0.f};
#pragma unroll
        for (int sl = 0; sl < 4; ++sl) {
            bf16x8 x = *(const bf16x8*)(MTp + (size_t)sl * B_ * 32768 + roff);
#pragma unroll
            for (int k = 0; k < 8; ++k) a8[k] += (float)x[k];
        }
        bf16x8 o;
#pragma unroll
        for (int k = 0; k < 8; ++k) o[k] = (bf16)(a8[k] * ldsLinv[q0 + k]);
        size_t woff = ((size_t)((b * 8 + (qo >> 2)) * 8 + (d >> 4))) * 512
                      + ((qo & 3) * 16 + (d & 15)) * 8;
        *(bf16x8*)(MTpn + woff) = o;
    }
}

// ---------------------------------------------------------------------------
// K5: A = Rinv*(P@Qb), Bt = Rinv*(P@M).
//   2-phase reg-staged LDS dbuf of Q/M panels; lane-linear conflict-free reads.
//   C read as exact fp32 from out block 0 (L3-resident). NT stores for out.
// grid (32 ctile, B), 256 thr (4 waves)
// ---------------------------------------------------------------------------
__global__ __launch_bounds__(256) void k_out(const bf16* __restrict__ Pp,
    const bf16* __restrict__ QbTp, const bf16* __restrict__ MTpn,
    const float* __restrict__ Rpart, float* __restrict__ out)
{
    __shared__ f32x4 smem4[2304];                       // 36864 B
    bf16* stage = (bf16*)smem4;                         // stage[2][8192] (32 KB)
    bf16 (*ldsA)[72] = (bf16(*)[72])smem4;              // epilogue-only (union)
    bf16 (*ldsB)[72] = (bf16(*)[72])((char*)smem4 + 18432);

    int b = blockIdx.y, ctile = blockIdx.x;
    int t = threadIdx.x, wid = t >> 6, lane = t & 63;
    int lr = lane & 15, lg = lane >> 4;
    int c0 = ctile * 64;

    const bf16* gsrc = (wid < 2 ? QbTp : MTpn) + (size_t)b * 32768
                       + (size_t)(wid & 1) * 2048 + lane * 8;
    int ldst = wid * 2048 + lane * 8;

    f32x4 rs = (f32x4){0.f, 0.f, 0.f, 0.f};
#pragma unroll
    for (int s = 0; s < 4; ++s)
        rs += *(const f32x4*)(Rpart + ((size_t)(b * 4 + s)) * LC + c0 + wid * 16 + lg * 4);
    f32x4 rv;
#pragma unroll
    for (int j = 0; j < 4; ++j) rv[j] = 1.0f / fmaxf(rs[j], 1e-30f);

    f32x4 accA[8], accB[8];
#pragma unroll
    for (int dt = 0; dt < 8; ++dt) {
        accA[dt] = (f32x4){0.f, 0.f, 0.f, 0.f};
        accB[dt] = (f32x4){0.f, 0.f, 0.f, 0.f};
    }
    const bf16* Ab = Pp + ((size_t)((b * 128 + ctile * 4 + wid) * 8)) * 512 + lane * 8;

    {
        bf16x8 g0 = *(const bf16x8*)(gsrc);
        bf16x8 g1 = *(const bf16x8*)(gsrc + 512);
        bf16x8 g2 = *(const bf16x8*)(gsrc + 1024);
        bf16x8 g3 = *(const bf16x8*)(gsrc + 1536);
        *(bf16x8*)&stage[ldst]        = g0;
        *(bf16x8*)&stage[ldst + 512]  = g1;
        *(bf16x8*)&stage[ldst + 1024] = g2;
        *(bf16x8*)&stage[ldst + 1536] = g3;
    }
    __syncthreads();

    for (int ks = 0; ks < 8; ++ks) {
        int cur = (ks & 1) * 8192;
        bf16x8 g0, g1, g2, g3;
        if (ks < 7) {
            const bf16* gs = gsrc + (size_t)(ks + 1) * 4096;
            g0 = *(const bf16x8*)(gs);
            g1 = *(const bf16x8*)(gs + 512);
            g2 = *(const bf16x8*)(gs + 1024);
            g3 = *(const bf16x8*)(gs + 1536);
        }
        bf16x8 a = *(const bf16x8*)(Ab + (size_t)ks * 512);
        int foff = cur + lane * 8;
#pragma unroll
        for (int dt = 0; dt < 8; ++dt) {
            bf16x8 bq = *(bf16x8*)&stage[foff + dt * 512];
            bf16x8 bm = *(bf16x8*)&stage[foff + 4096 + dt * 512];
            accA[dt] = MFMA16(a, bq, accA[dt]);
            accB[dt] = MFMA16(a, bm, accB[dt]);
        }
        if (ks < 7) {
            int nb = cur ^ 8192;
            *(bf16x8*)&stage[nb + ldst]        = g0;
            *(bf16x8*)&stage[nb + ldst + 512]  = g1;
            *(bf16x8*)&stage[nb + ldst + 1024] = g2;
            *(bf16x8*)&stage[nb + ldst + 1536] = g3;
        }
        __syncthreads();
    }

#pragma unroll
    for (int dt = 0; dt < 8; ++dt) {
        f32x4 a4 = accA[dt] * rv;
        f32x4 b4 = accB[dt] * rv;
        bf16x4 pa = { (bf16)a4[0], (bf16)a4[1], (bf16)a4[2], (bf16)a4[3] };
        bf16x4 pb = { (bf16)b4[0], (bf16)b4[1], (bf16)b4[2], (bf16)b4[3] };
        *(bf16x4*)&ldsA[dt * 16 + lr][wid * 16 + lg * 4] = pa;
        *(bf16x4*)&ldsB[dt * 16 + lr][wid * 16 + lg * 4] = pb;
    }
    __syncthreads();

    float* obase = out + ((size_t)b * 512) * LC;
#pragma unroll
    for (int pass = 0; pass < 8; ++pass) {
        int d = pass * 16 + (t >> 4);
        int cq = (t & 15) * 4;
        bf16x4 av = *(bf16x4*)&ldsA[d][cq];
        bf16x4 bv = *(bf16x4*)&ldsB[d][cq];
        f32x4 c4 = *(const f32x4*)(obase + (size_t)d * LC + c0 + cq);
        f32x4 a4 = {(float)av[0], (float)av[1], (float)av[2], (float)av[3]};
        f32x4 b4 = {(float)bv[0], (float)bv[1], (float)bv[2], (float)bv[3]};
        __builtin_nontemporal_store(a4, (f32x4*)(obase + (size_t)(128 + d) * LC + c0 + cq));
        __builtin_nontemporal_store(c4 * a4, (f32x4*)(obase + (size_t)(256 + d) * LC + c0 + cq));
        __builtin_nontemporal_store(c4 * b4, (f32x4*)(obase + (size_t)(384 + d) * LC + c0 + cq));
    }
}

// ---------------------------------------------------------------------------
extern "C" void kernel_launch(void* const* d_in, const int* in_sizes, int n_in,
                              void* d_out, int out_size, void* d_ws, size_t ws_size,
                              hipStream_t stream)
{
    const float* C     = (const float*)d_in[0];
    const float* Q     = (const float*)d_in[1];
    const float* Cmask = (const float*)d_in[2];
    const float* Qmask = (const float*)d_in[3];
    const float* w4C   = (const float*)d_in[4];
    const float* w4Q   = (const float*)d_in[5];
    const float* w4mlu = (const float*)d_in[6];
    const float* bias  = (const float*)d_in[7];
    float* out = (float*)d_out;

    char* ws = (char*)d_ws;
    size_t off = 0;
    auto alloc = [&](size_t bytes) -> char* {
        char* p = ws + off;
        off += (bytes + 255) & ~(size_t)255;
        return p;
    };
    bf16* Cwp   = (bf16*)alloc((size_t)B_ * LC * DD * 2);
    bf16* CbTmp = (bf16*)alloc((size_t)B_ * LC * DD * 2);
    bf16* Qbp   = (bf16*)alloc((size_t)B_ * LQ * DD * 2);
    bf16* QbTp  = (bf16*)alloc((size_t)B_ * LQ * DD * 2);
    bf16* Pp    = (bf16*)alloc((size_t)B_ * LC * LQ * 2);
    bf16* MTp   = (bf16*)alloc((size_t)4 * B_ * DD * LQ * 2);
    bf16* MTpn  = (bf16*)alloc((size_t)B_ * DD * LQ * 2);
    float* sub0 = (float*)alloc((size_t)B_ * LC * 4);
    float* sub1 = (float*)alloc((size_t)B_ * LQ * 4);
    float* Rpart = (float*)alloc((size_t)B_ * 4 * LC * 4);
    float* Lpart = (float*)alloc((size_t)B_ * 64 * LQ * 4);
    (void)ws_size; (void)in_sizes; (void)n_in; (void)out_size;

    hipLaunchKernelGGL(k_prep, dim3(2304), dim3(256), 0, stream,
                       C, Q, Cmask, w4C, w4Q, w4mlu, Cwp, CbTmp, Qbp, QbTp, sub0, sub1, out);
    hipLaunchKernelGGL(k_s, dim3(16, 4, B_), dim3(256), 0, stream,
                       Cwp, Qbp, sub0, sub1, Qmask, Cmask, bias, Pp, Rpart, Lpart);
    hipLaunchKernelGGL(k_m, dim3(4, 4, B_), dim3(256), 0, stream, CbTmp, Pp, MTp);
    hipLaunchKernelGGL(k_m2, dim3(4, B_), dim3(256), 0, stream, MTp, Lpart, MTpn);
    hipLaunchKernelGGL(k_out, dim3(32, B_), dim3(256), 0, stream,
                       Pp, QbTp, MTpn, Rpart, out);
}